// Round 9
// baseline (339.334 us; speedup 1.0000x reference)
//
#include <hip/hip_runtime.h>
#include <hip/hip_bf16.h>
#include <math.h>

typedef __bf16 bf16_t;
typedef __bf16 bf16x8 __attribute__((ext_vector_type(8)));
typedef __bf16 bf16x4 __attribute__((ext_vector_type(4)));
typedef short short4v __attribute__((ext_vector_type(4)));
typedef float f32x4 __attribute__((ext_vector_type(4)));

__device__ __forceinline__ f32x4 mfma_k32(bf16x8 a, bf16x8 b, f32x4 c) {
    return __builtin_amdgcn_mfma_f32_16x16x32_bf16(a, b, c, 0, 0, 0);
}

__device__ __forceinline__ f32x4 mfma_k16(bf16x4 a, bf16x4 b, f32x4 c) {
#if __has_builtin(__builtin_amdgcn_mfma_f32_16x16x16_bf16)
    return __builtin_amdgcn_mfma_f32_16x16x16_bf16(a, b, c, 0, 0, 0);
#elif __has_builtin(__builtin_amdgcn_mfma_f32_16x16x16bf16_1k)
    short4v as, bs;
    __builtin_memcpy(&as, &a, 8);
    __builtin_memcpy(&bs, &b, 8);
    return __builtin_amdgcn_mfma_f32_16x16x16bf16_1k(as, bs, c, 0, 0, 0);
#else
    f32x4 d = c;
    asm volatile("v_mfma_f32_16x16x16_bf16 %0, %1, %2, %0" : "+v"(d) : "v"(a), "v"(b));
    return d;
#endif
}

// raw v_exp_f32 (exp2): avoid OCML guard code around exp2f
__device__ __forceinline__ float fast_exp2(float x) {
#if __has_builtin(__builtin_amdgcn_exp2f)
    return __builtin_amdgcn_exp2f(x);
#else
    float r;
    asm("v_exp_f32 %0, %1" : "=v"(r) : "v"(x));
    return r;
#endif
}

// async global->LDS, 16B/lane; LDS dest = wave-uniform base + lane*16
__device__ __forceinline__ void async16(const bf16_t* g, __bf16* l) {
    __builtin_amdgcn_global_load_lds(
        (const __attribute__((address_space(1))) void*)g,
        (__attribute__((address_space(3))) void*)l, 16, 0, 0);
}

// XOR-swizzle: 16B chunks within each 64-col group, keyed by row&7 (global-side)
__device__ __forceinline__ int swz_col(int col, int row) {
    return (col & ~63) | ((((col >> 3) & 7) ^ (row & 7)) << 3) | (col & 7);
}

__device__ __forceinline__ bf16x8 cvt8(float4 a, float4 b) {
    bf16x8 w;
    w[0]=(__bf16)a.x; w[1]=(__bf16)a.y; w[2]=(__bf16)a.z; w[3]=(__bf16)a.w;
    w[4]=(__bf16)b.x; w[5]=(__bf16)b.y; w[6]=(__bf16)b.z; w[7]=(__bf16)b.w;
    return w;
}

// ---------------------------------------------------------------------------
// fp32 -> bf16 swizzled convert, W only (R7 lesson: keep this kernel).
// ---------------------------------------------------------------------------
__global__ __launch_bounds__(256) void cvt_W(const float* __restrict__ Wq,
                                             const float* __restrict__ Wk,
                                             const float* __restrict__ Wv,
                                             const float* __restrict__ Wo,
                                             bf16_t* __restrict__ Wc) {
    const int b2 = blockIdx.x;
    const int m = b2 >> 7;                   // which W
    const float* src = m == 0 ? Wq : m == 1 ? Wk : m == 2 ? Wv : Wo;
    const float sc = (m == 0) ? 0.125f * 1.44269504088896f : 1.0f;
    size_t i = ((size_t)(b2 & 127) * 256 + threadIdx.x) * 8;
    int row = (int)(i >> 9), col = (int)(i & 511);
    float4 a0 = *(const float4*)(src + i), a1 = *(const float4*)(src + i + 4);
    bf16x8 o;
    o[0]=(__bf16)(a0.x*sc); o[1]=(__bf16)(a0.y*sc); o[2]=(__bf16)(a0.z*sc); o[3]=(__bf16)(a0.w*sc);
    o[4]=(__bf16)(a1.x*sc); o[5]=(__bf16)(a1.y*sc); o[6]=(__bf16)(a1.z*sc); o[7]=(__bf16)(a1.w*sc);
    *(bf16x8*)(Wc + (size_t)m * 262144 + (size_t)row * 512 + swz_col(col, row)) = o;
}

// ---------------------------------------------------------------------------
// 128x128-tile NT GEMM (m97 structure), per-operand staging (proven R4/R5):
//   AF32/BF32 = 1: fp32 operand; reg-load 32B/lane, cvt, Latin-square-swizzled
//     ds_write_b128. 0: pre-swizzled bf16; global_load_lds direct.
// ---------------------------------------------------------------------------
template<int MODE, int AF32, int BF32>
__device__ __forceinline__ void gemm128_body(const bf16_t* __restrict__ Ab,
                                             const float* __restrict__ Af,
                                             const bf16_t* __restrict__ Bb,
                                             const float* __restrict__ Bf,
                                             void* __restrict__ outp,
                                             int m0, int n0) {
    __shared__ __bf16 Asm[128 * 64];
    __shared__ __bf16 Bsm[128 * 64];
    const int tid  = threadIdx.x;
    const int wave = tid >> 6;
    const int lane = tid & 63;
    const int quad = lane >> 4;
    const int l16  = lane & 15;
    const int swz  = l16 & 7;
    const int r8 = lane >> 3;
    const int c8 = (lane & 7) * 8;
    const int mrow0 = (wave & 1) * 64;
    const int ncol0 = (wave >> 1) * 64;

    f32x4 acc[4][4];
    for (int i = 0; i < 4; ++i)
        for (int j = 0; j < 4; ++j) acc[i][j] = (f32x4){0.f, 0.f, 0.f, 0.f};

    for (int kt = 0; kt < 512; kt += 64) {
        __syncthreads();
        for (int j = 0; j < 4; ++j) {
            const int rl = wave * 32 + j * 8 + r8;
            if (AF32) {
                const float* s = Af + (size_t)(m0 + rl) * 512 + kt + c8;
                float4 v0 = *(const float4*)s, v1 = *(const float4*)(s + 4);
                *(bf16x8*)&Asm[rl * 64 + (((lane & 7) ^ r8) << 3)] = cvt8(v0, v1);
            } else {
                async16(Ab + (size_t)(m0 + rl) * 512 + kt + c8,
                        &Asm[(wave * 32 + j * 8) * 64]);
            }
            if (BF32) {
                const float* s = Bf + (size_t)(n0 + rl) * 512 + kt + c8;
                float4 v0 = *(const float4*)s, v1 = *(const float4*)(s + 4);
                *(bf16x8*)&Bsm[rl * 64 + (((lane & 7) ^ r8) << 3)] = cvt8(v0, v1);
            } else {
                async16(Bb + (size_t)(n0 + rl) * 512 + kt + c8,
                        &Bsm[(wave * 32 + j * 8) * 64]);
            }
        }
        __syncthreads();

        for (int ks = 0; ks < 2; ++ks) {
            bf16x8 af[4];
            for (int mt = 0; mt < 4; ++mt)
                af[mt] = *(const bf16x8*)&Asm[(mrow0 + mt * 16 + l16) * 64 + ((ks * 4 + quad) ^ swz) * 8];
            for (int nt = 0; nt < 4; ++nt) {
                bf16x8 bf = *(const bf16x8*)&Bsm[(ncol0 + nt * 16 + l16) * 64 + ((ks * 4 + quad) ^ swz) * 8];
                for (int mt = 0; mt < 4; ++mt)
                    acc[mt][nt] = mfma_k32(af[mt], bf, acc[mt][nt]);
            }
        }
    }

    if (MODE == 0) {
        bf16_t* out = (bf16_t*)outp;
        for (int nt = 0; nt < 4; ++nt) {
            int e = n0 + ncol0 + nt * 16 + l16;
            int h = e >> 6, el = e & 63;
            for (int mt = 0; mt < 4; ++mt)
                for (int r = 0; r < 4; ++r) {
                    int row = m0 + mrow0 + mt * 16 + quad * 4 + r;   // b*4096+s
                    int b = row >> 12, s = row & 4095;
                    int elp = (((el >> 3) ^ (row & 7)) << 3) | (el & 7);
                    out[(((size_t)(b * 8 + h)) * 4096 + s) * 64 + elp] = (bf16_t)acc[mt][nt][r];
                }
        }
    } else {
        bf16_t* out = (bf16_t*)outp;
        for (int nt = 0; nt < 4; ++nt) {
            int s_g = n0 + ncol0 + nt * 16 + l16;
            int b = s_g >> 12;
            int sbase = (s_g & 4095) & ~63;
            int f = 16 * ((l16 >> 2) & 3) + 4 * nt + (l16 & 3);
            for (int mt = 0; mt < 4; ++mt)
                for (int r = 0; r < 4; ++r) {
                    int e_g = m0 + mrow0 + mt * 16 + quad * 4 + r;
                    int h = e_g >> 6, el = e_g & 63;
                    int col = sbase | ((((f >> 3) ^ (e_g & 7)) & 7) << 3) | (f & 7);
                    out[(((size_t)(b * 8 + h)) * 64 + el) * 4096 + col] = (bf16_t)acc[mt][nt][r];
                }
        }
    }
}

// grid (256,1,3); XCD-sibling swizzle: same-A-stripe blocks (4 y's) get ids
// 8 apart -> same XCD round-robin -> stripe L2-served.
__global__ __launch_bounds__(256) void proj_fused(const float* __restrict__ q,
                                                  const float* __restrict__ k,
                                                  const float* __restrict__ v,
                                                  const bf16_t* __restrict__ Wc,
                                                  bf16_t* __restrict__ qh,
                                                  bf16_t* __restrict__ kh,
                                                  bf16_t* __restrict__ vh) {
    const int f = blockIdx.x;
    const int y = (f >> 3) & 3;
    const int x = (f & 7) | ((f >> 5) << 3);
    const int z = blockIdx.z;
    const bf16_t* W = Wc + (size_t)z * 262144;
    if (z == 0)
        gemm128_body<0, 1, 0>(nullptr, q, W, nullptr, qh, x * 128, y * 128);
    else if (z == 1)
        gemm128_body<0, 1, 0>(nullptr, k, W, nullptr, kh, x * 128, y * 128);
    else
        gemm128_body<1, 0, 1>(W, nullptr, nullptr, v, vh, y * 128, x * 128);
}

// ---------------------------------------------------------------------------
// Final GEMM: fused z-combine + softmax normalization in A-staging (proven
// R4), B = pre-converted bf16 Wo via async16 (R5 config), XCD swizzle.
// ---------------------------------------------------------------------------
__global__ __launch_bounds__(256) void gemm_final(const bf16_t* __restrict__ Op,
                                                  const float* __restrict__ Lp,
                                                  const bf16_t* __restrict__ B,
                                                  float* __restrict__ out) {
    __shared__ __bf16 Asm[128 * 64];
    __shared__ __bf16 Bsm[128 * 64];
    const int fb = blockIdx.x;
    const int m0 = ((fb & 7) | ((fb >> 5) << 3)) * 128;
    const int n0 = ((fb >> 3) & 3) * 128;
    const int tid  = threadIdx.x;
    const int wave = tid >> 6;
    const int lane = tid & 63;
    const int quad = lane >> 4;
    const int l16  = lane & 15;
    const int swz  = l16 & 7;
    const int r8 = lane >> 3;
    const int c8 = (lane & 7) * 8;
    const int mrow0 = (wave & 1) * 64;
    const int ncol0 = (wave >> 1) * 64;

    f32x4 acc[4][4];
    for (int i = 0; i < 4; ++i)
        for (int j = 0; j < 4; ++j) acc[i][j] = (f32x4){0.f, 0.f, 0.f, 0.f};

    for (int kt = 0; kt < 512; kt += 64) {
        const int h = kt >> 6;
        __syncthreads();
        for (int j = 0; j < 4; ++j)
            async16(B + (size_t)(n0 + wave * 32 + j * 8 + r8) * 512 + kt + c8,
                    &Bsm[(wave * 32 + j * 8) * 64]);
        for (int j = 0; j < 4; ++j) {
            const int rl  = wave * 32 + j * 8 + r8;
            const int row = m0 + rl;                 // b*4096 + s
            const int b   = row >> 12, sp = row & 4095;
            const size_t lidx = (size_t)(b * 8 + h) * 4096 + sp;
            bf16x8 a0 = *(const bf16x8*)(Op + lidx * 64 + c8);
            bf16x8 a1 = *(const bf16x8*)(Op + 4194304 + lidx * 64 + c8);
            float inv = 1.0f / (Lp[lidx] + Lp[65536 + lidx]);
            bf16x8 w;
            for (int i = 0; i < 8; ++i)
                w[i] = (bf16_t)(((float)a0[i] + (float)a1[i]) * inv);
            *(bf16x8*)&Asm[rl * 64 + (((lane & 7) ^ r8) << 3)] = w;
        }
        __syncthreads();

        for (int ks = 0; ks < 2; ++ks) {
            bf16x8 af[4];
            for (int mt = 0; mt < 4; ++mt)
                af[mt] = *(const bf16x8*)&Asm[(mrow0 + mt * 16 + l16) * 64 + ((ks * 4 + quad) ^ swz) * 8];
            for (int nt = 0; nt < 4; ++nt) {
                bf16x8 bf = *(const bf16x8*)&Bsm[(ncol0 + nt * 16 + l16) * 64 + ((ks * 4 + quad) ^ swz) * 8];
                for (int mt = 0; mt < 4; ++mt)
                    acc[mt][nt] = mfma_k32(af[mt], bf, acc[mt][nt]);
            }
        }
    }

    for (int nt = 0; nt < 4; ++nt) {
        int n = n0 + ncol0 + nt * 16 + l16;
        for (int mt = 0; mt < 4; ++mt)
            for (int r = 0; r < 4; ++r) {
                int row = m0 + mrow0 + mt * 16 + quad * 4 + r;
                out[(size_t)row * 512 + n] = acc[mt][nt][r];
            }
    }
}

// ---------------------------------------------------------------------------
// Causal flash attention v11: v7 compute/softmax/PV/combine VERBATIM (frozen;
// lsum back on VALU + shfl — R8's MFMA-lsum regressed). ONE change: T14
// async-STAGE split. v7 staged K/V via global_load_lds between two barriers,
// exposing full load latency every step (the ~25% non-pipe cycle gap).
// v11 preloads the next tile into registers (8x global_load_dwordx4, issued
// right after the compute barrier so they fly UNDER the MFMA/exp2 phase),
// then ds_write_b128 them at the next step. LDS layout byte-identical to
// global_load_lds placement (base + lane*16) -> readers untouched; writes
// are contiguous-16B (2-way/free). kreg/vreg fully unrolled (rule #20).
// Tripwire: WRITE_SIZE > 50 MB = spill => revert to v7.
// ---------------------------------------------------------------------------
__global__ __launch_bounds__(256, 4) void attn_kernel(const bf16_t* __restrict__ qh,
                                                      const bf16_t* __restrict__ kh,
                                                      const bf16_t* __restrict__ vh,
                                                      bf16_t* __restrict__ Opart,
                                                      float* __restrict__ Lpart) {
    __shared__ __bf16 SM[16384];            // 32 KB: K panels [2][64][64] + V panels
    __bf16* KSM = &SM[0];
    __bf16* VSM = &SM[8192];
    float* Osc = (float*)SM;                // 16.6 KB leg-end scratch [q][65]
    float* Lsc = (float*)&SM[8320];         // 256 B lsum scratch [q] (byte 16640)

    const int id   = blockIdx.x;
    const int bh   = ((id & 7) << 1) | ((id >> 3) & 1);   // XCD-grouped
    const int pair = (id >> 4) & 31;
    const int z    = (id >> 9) & 1;

    const int tid  = threadIdx.x;
    const int wave = tid >> 6;
    const int g2   = wave >> 1;             // K-panel parity within step
    const int wl   = wave & 1;              // query half
    const int lane = tid & 63;
    const int quad = lane >> 4;
    const int l16  = lane & 15;
    const int swz  = l16 & 7;
    const size_t base = (size_t)bh * 4096 * 64;
    const int r8 = lane >> 3;
    const int c8 = (lane & 7) * 8;

    bf16_t* Op = Opart + (size_t)z * 4194304;
    float*  Lp = Lpart + z * 65536;

    for (int leg = 0; leg < 2; ++leg) {
        const int qt = leg ? (63 - pair) : pair;
        const int q0 = qt * 64;

        bf16x8 qf[2][2];
        for (int g = 0; g < 2; ++g) {
            const bf16_t* qp = qh + base + (size_t)(q0 + wl * 32 + g * 16 + l16) * 64;
            qf[g][0] = *(const bf16x8*)(qp + ((quad ^ swz) * 8));
            qf[g][1] = *(const bf16x8*)(qp + (((4 + quad) ^ swz) * 8));
        }

        f32x4 o[2][4];
        for (int g = 0; g < 2; ++g)
            for (int i = 0; i < 4; ++i) o[g][i] = (f32x4){0.f, 0.f, 0.f, 0.f};
        float lsum[2] = {0.f, 0.f};

        const int S  = (qt + 2) >> 1;       // total 128-key steps of this leg
        const int Sh = (S + 1) >> 1;        // z=0 takes [0,Sh), z=1 takes [Sh,S)
        const int it0 = z ? Sh : 0;
        const int it1 = z ? S : Sh;

        // T14 preload: first tile -> registers (32 VGPRs, static-indexed)
        bf16x8 kreg[4], vreg[4];
        {
            const int j0p = it0 * 128;
#pragma unroll
            for (int p = 0; p < 2; ++p)
#pragma unroll
                for (int j = 0; j < 2; ++j) {
                    const int row = wave * 16 + j * 8 + r8;
                    kreg[p * 2 + j] = *(const bf16x8*)(kh + base + (size_t)(j0p + p * 64 + row) * 64 + c8);
                    vreg[p * 2 + j] = *(const bf16x8*)(vh + (size_t)(bh * 64 + row) * 4096 + j0p + p * 64 + c8);
                }
        }

        for (int it = it0; it < it1; ++it) {
            const int j0 = it * 128;
            __syncthreads();                 // prev step's LDS reads done
            // commit staged regs to LDS (compiler inserts vmcnt wait)
#pragma unroll
            for (int p = 0; p < 2; ++p)
#pragma unroll
                for (int j = 0; j < 2; ++j) {
                    *(bf16x8*)(KSM + (p * 64 + wave * 16 + j * 8) * 64 + lane * 8) = kreg[p * 2 + j];
                    *(bf16x8*)(VSM + (p * 64 + wave * 16 + j * 8) * 64 + lane * 8) = vreg[p * 2 + j];
                }
            __syncthreads();
            // issue next tile's loads — they fly under this step's compute
            if (it + 1 < it1) {
                const int j0n = j0 + 128;
#pragma unroll
                for (int p = 0; p < 2; ++p)
#pragma unroll
                    for (int j = 0; j < 2; ++j) {
                        const int row = wave * 16 + j * 8 + r8;
                        kreg[p * 2 + j] = *(const bf16x8*)(kh + base + (size_t)(j0n + p * 64 + row) * 64 + c8);
                        vreg[p * 2 + j] = *(const bf16x8*)(vh + (size_t)(bh * 64 + row) * 4096 + j0n + p * 64 + c8);
                    }
            }

            const int pp = g2;
            const int koff = j0 + pp * 64 - q0;
            if (koff > wl * 32 + 31) continue;     // fully masked for this wave

            // S^T = K·Q^T (C: col=query=l16, row=key=nt*16+quad*4+r)
            f32x4 st[2][4];
            for (int nt = 0; nt < 4; ++nt) {
                const __bf16* kr = KSM + (pp * 64 + nt * 16 + l16) * 64;
                bf16x8 kf0 = *(const bf16x8*)(kr + ((quad ^ swz) * 8));
                bf16x8 kf1 = *(const bf16x8*)(kr + (((4 + quad) ^ swz) * 8));
                for (int g = 0; g < 2; ++g) {
                    f32x4 zz = (f32x4){0.f, 0.f, 0.f, 0.f};
                    zz = mfma_k32(kf0, qf[g][0], zz);
                    zz = mfma_k32(kf1, qf[g][1], zz);
                    st[g][nt] = zz;
                }
            }

            // fixed-base softmax: p = exp2(st)
            bf16x4 pf[2][4];
            for (int g = 0; g < 2; ++g) {
                const int qb = wl * 32 + g * 16;
                if (koff + 63 <= qb) {
                    for (int nt = 0; nt < 4; ++nt)
                        for (int r = 0; r < 4; ++r) {
                            float p = fast_exp2(st[g][nt][r]);
                            lsum[g] += p;
                            pf[g][nt][r] = (bf16_t)p;
                        }
                } else {
                    const int qrow = qb + l16;
                    for (int nt = 0; nt < 4; ++nt)
                        for (int r = 0; r < 4; ++r) {
                            int key = nt * 16 + quad * 4 + r;
                            float p = (key + koff <= qrow) ? fast_exp2(st[g][nt][r]) : 0.f;
                            lsum[g] += p;
                            pf[g][nt][r] = (bf16_t)p;
                        }
                }
            }

            // O += P·V (P register-resident)
            for (int dt = 0; dt < 4; ++dt)
                for (int kt2 = 0; kt2 < 2; ++kt2) {
                    bf16x8 vf = *(const bf16x8*)&VSM[(pp * 64 + dt * 16 + l16) * 64 + (((2 * quad + kt2) ^ swz) * 8)];
                    bf16x4 vlo = {vf[0], vf[1], vf[2], vf[3]};
                    bf16x4 vhi = {vf[4], vf[5], vf[6], vf[7]};
                    for (int g = 0; g < 2; ++g) {
                        o[g][dt] = mfma_k16(pf[g][2 * kt2], vlo, o[g][dt]);
                        o[g][dt] = mfma_k16(pf[g][2 * kt2 + 1], vhi, o[g][dt]);
                    }
                }
        }

        // ---- combine K-parity partials within block, write leg partials ----
        __syncthreads();                    // all K/V LDS reads done
        if (g2 == 1) {
            for (int g = 0; g < 2; ++g) {
                float ls = lsum[g];
                ls += __shfl_xor(ls, 16);
                ls += __shfl_xor(ls, 32);
                const int qb = wl * 32 + g * 16;
                Lsc[qb + l16] = ls;
                for (int dt = 0; dt < 4; ++dt)
                    for (int r = 0; r < 4; ++r)
                        Osc[(qb + quad * 4 + r) * 65 + dt * 16 + l16] = o[g][dt][r];
            }
        }
        __syncthreads();
        if (g2 == 0) {
            for (int g = 0; g < 2; ++g) {
                float ls = lsum[g];
                ls += __shfl_xor(ls, 16);
                ls += __shfl_xor(ls, 32);
                const int qb = wl * 32 + g * 16;
                ls += Lsc[qb + l16];
                Lsc[qb + l16] = ls;         // total lsum for this z
                for (int dt = 0; dt < 4; ++dt)
                    for (int r = 0; r < 4; ++r) {
                        int idx = (qb + quad * 4 + r) * 65 + dt * 16 + l16;
                        Osc[idx] = o[g][dt][r] + Osc[idx];
                    }
            }
        }
        __syncthreads();
        // repack: contiguous bf16 partial rows [q][e] + fp32 lsum
        {
            const int q  = tid >> 2;
            const int e0 = (tid & 3) * 16;
            bf16x8 w0, w1;
            for (int i = 0; i < 8; ++i) {
                w0[i] = (bf16_t)Osc[q * 65 + e0 + i];
                w1[i] = (bf16_t)Osc[q * 65 + e0 + 8 + i];
            }
            size_t slot = ((size_t)(bh * 64 + qt)) * 4096 + q * 64 + e0;
            *(bf16x8*)&Op[slot]     = w0;
            *(bf16x8*)&Op[slot + 8] = w1;
            if (tid < 64) Lp[(bh * 64 + qt) * 64 + tid] = Lsc[tid];
        }
        // next leg's first __syncthreads() protects Osc/Lsc reuse
    }
}

// ---------------------------------------------------------------------------
extern "C" void kernel_launch(void* const* d_in, const int* in_sizes, int n_in,
                              void* d_out, int out_size, void* d_ws, size_t ws_size,
                              hipStream_t stream) {
    const float* q  = (const float*)d_in[0];
    const float* k  = (const float*)d_in[1];
    const float* v  = (const float*)d_in[2];
    const float* Wq = (const float*)d_in[3];
    const float* Wk = (const float*)d_in[4];
    const float* Wv = (const float*)d_in[5];
    const float* Wo = (const float*)d_in[6];
    float* out = (float*)d_out;

    bf16_t* ws = (bf16_t*)d_ws;
    const size_t R = (size_t)8192 * 512;   // 4.19M elems = 8.39 MB per region
    bf16_t* opart = ws + R;          // R1+R2: Opart z0/z1
    bf16_t* vh = ws + 3 * R;         // R3: V^T heads
    bf16_t* Wc = ws + 4 * R;         // +2 MB bf16 weights (Wq pre-scaled)
    float*  Lp = (float*)(ws + 4 * R + 1048576);  // +0.5 MB lsum partials
    bf16_t* qh = (bf16_t*)d_out;     // qh/kh in d_out, dead before final GEMM
    bf16_t* kh = (bf16_t*)d_out + R;

    cvt_W<<<dim3(512), dim3(256), 0, stream>>>(Wq, Wk, Wv, Wo, Wc);
    proj_fused<<<dim3(256, 1, 3), dim3(256), 0, stream>>>(q, k, v, Wc, qh, kh, vh);
    attn_kernel<<<dim3(1024), dim3(256), 0, stream>>>(qh, kh, vh, opart, Lp);
    gemm_final<<<dim3(256), dim3(256), 0, stream>>>(opart, Lp, Wc + 3 * 262144, out);
}

// Round 10
// 245.365 us; speedup vs baseline: 1.3830x; 1.3830x over previous
//
#include <hip/hip_runtime.h>
#include <hip/hip_bf16.h>
#include <math.h>

typedef __bf16 bf16_t;
typedef __bf16 bf16x8 __attribute__((ext_vector_type(8)));
typedef __bf16 bf16x4 __attribute__((ext_vector_type(4)));
typedef short short4v __attribute__((ext_vector_type(4)));
typedef float f32x4 __attribute__((ext_vector_type(4)));

__device__ __forceinline__ f32x4 mfma_k32(bf16x8 a, bf16x8 b, f32x4 c) {
    return __builtin_amdgcn_mfma_f32_16x16x32_bf16(a, b, c, 0, 0, 0);
}

__device__ __forceinline__ f32x4 mfma_k16(bf16x4 a, bf16x4 b, f32x4 c) {
#if __has_builtin(__builtin_amdgcn_mfma_f32_16x16x16_bf16)
    return __builtin_amdgcn_mfma_f32_16x16x16_bf16(a, b, c, 0, 0, 0);
#elif __has_builtin(__builtin_amdgcn_mfma_f32_16x16x16bf16_1k)
    short4v as, bs;
    __builtin_memcpy(&as, &a, 8);
    __builtin_memcpy(&bs, &b, 8);
    return __builtin_amdgcn_mfma_f32_16x16x16bf16_1k(as, bs, c, 0, 0, 0);
#else
    f32x4 d = c;
    asm volatile("v_mfma_f32_16x16x16_bf16 %0, %1, %2, %0" : "+v"(d) : "v"(a), "v"(b));
    return d;
#endif
}

// raw v_exp_f32 (exp2): avoid OCML guard code around exp2f
__device__ __forceinline__ float fast_exp2(float x) {
#if __has_builtin(__builtin_amdgcn_exp2f)
    return __builtin_amdgcn_exp2f(x);
#else
    float r;
    asm("v_exp_f32 %0, %1" : "=v"(r) : "v"(x));
    return r;
#endif
}

// async global->LDS, 16B/lane; LDS dest = wave-uniform base + lane*16
__device__ __forceinline__ void async16(const bf16_t* g, __bf16* l) {
    __builtin_amdgcn_global_load_lds(
        (const __attribute__((address_space(1))) void*)g,
        (__attribute__((address_space(3))) void*)l, 16, 0, 0);
}

// XOR-swizzle: 16B chunks within each 64-col group, keyed by row&7 (global-side)
__device__ __forceinline__ int swz_col(int col, int row) {
    return (col & ~63) | ((((col >> 3) & 7) ^ (row & 7)) << 3) | (col & 7);
}

__device__ __forceinline__ bf16x8 cvt8(float4 a, float4 b) {
    bf16x8 w;
    w[0]=(__bf16)a.x; w[1]=(__bf16)a.y; w[2]=(__bf16)a.z; w[3]=(__bf16)a.w;
    w[4]=(__bf16)b.x; w[5]=(__bf16)b.y; w[6]=(__bf16)b.z; w[7]=(__bf16)b.w;
    return w;
}

// ---------------------------------------------------------------------------
// fp32 -> bf16 swizzled convert, W only (R7 lesson: keep this kernel).
// ---------------------------------------------------------------------------
__global__ __launch_bounds__(256) void cvt_W(const float* __restrict__ Wq,
                                             const float* __restrict__ Wk,
                                             const float* __restrict__ Wv,
                                             const float* __restrict__ Wo,
                                             bf16_t* __restrict__ Wc) {
    const int b2 = blockIdx.x;
    const int m = b2 >> 7;                   // which W
    const float* src = m == 0 ? Wq : m == 1 ? Wk : m == 2 ? Wv : Wo;
    const float sc = (m == 0) ? 0.125f * 1.44269504088896f : 1.0f;
    size_t i = ((size_t)(b2 & 127) * 256 + threadIdx.x) * 8;
    int row = (int)(i >> 9), col = (int)(i & 511);
    float4 a0 = *(const float4*)(src + i), a1 = *(const float4*)(src + i + 4);
    bf16x8 o;
    o[0]=(__bf16)(a0.x*sc); o[1]=(__bf16)(a0.y*sc); o[2]=(__bf16)(a0.z*sc); o[3]=(__bf16)(a0.w*sc);
    o[4]=(__bf16)(a1.x*sc); o[5]=(__bf16)(a1.y*sc); o[6]=(__bf16)(a1.z*sc); o[7]=(__bf16)(a1.w*sc);
    *(bf16x8*)(Wc + (size_t)m * 262144 + (size_t)row * 512 + swz_col(col, row)) = o;
}

// ---------------------------------------------------------------------------
// 128x128-tile NT GEMM, DOUBLE-BUFFERED (T3 2-phase minimum): one barrier
// per K-step; stage of tile t+1 issued right after the barrier so it flies
// under tile t's MFMA. LDS 64KB -> 2 blocks/CU; __launch_bounds__(256,2)
// raises VGPR budget to 256 so fp32-operand reg-prefetch cannot spill
// (the R9 attn lesson: at (256,4) the 128-reg cap forced scratch).
// Race-freedom: stage always targets buf[c^1] while compute reads buf[c];
// the single barrier separates each buffer's last read from its next write.
// ---------------------------------------------------------------------------
template<int MODE, int AF32, int BF32>
__device__ __forceinline__ void gemm128_dbuf(const bf16_t* __restrict__ Ab,
                                             const float* __restrict__ Af,
                                             const bf16_t* __restrict__ Bb,
                                             const float* __restrict__ Bf,
                                             void* __restrict__ outp,
                                             int m0, int n0) {
    __shared__ __bf16 Asm[2][128 * 64];
    __shared__ __bf16 Bsm[2][128 * 64];
    const int tid  = threadIdx.x;
    const int wave = tid >> 6;
    const int lane = tid & 63;
    const int quad = lane >> 4;
    const int l16  = lane & 15;
    const int swz  = l16 & 7;
    const int r8 = lane >> 3;
    const int c8 = (lane & 7) * 8;
    const int mrow0 = (wave & 1) * 64;
    const int ncol0 = (wave >> 1) * 64;
    const int wswz = ((lane & 7) ^ r8) << 3;

    f32x4 acc[4][4];
    for (int i = 0; i < 4; ++i)
        for (int j = 0; j < 4; ++j) acc[i][j] = (f32x4){0.f, 0.f, 0.f, 0.f};

    float4 apre[4][2], bpre[4][2];

    // prologue: issue kt=0 stage
#pragma unroll
    for (int j = 0; j < 4; ++j) {
        const int rl = wave * 32 + j * 8 + r8;
        if (AF32) {
            const float* s = Af + (size_t)(m0 + rl) * 512 + c8;
            apre[j][0] = *(const float4*)s; apre[j][1] = *(const float4*)(s + 4);
        } else {
            async16(Ab + (size_t)(m0 + rl) * 512 + c8, &Asm[0][(wave * 32 + j * 8) * 64]);
        }
        if (BF32) {
            const float* s = Bf + (size_t)(n0 + rl) * 512 + c8;
            bpre[j][0] = *(const float4*)s; bpre[j][1] = *(const float4*)(s + 4);
        } else {
            async16(Bb + (size_t)(n0 + rl) * 512 + c8, &Bsm[0][(wave * 32 + j * 8) * 64]);
        }
    }

    for (int it = 0; it < 8; ++it) {
        const int cb = it & 1;
        // commit reg-prefetched fp32 operands into buf cb
        if (AF32) {
#pragma unroll
            for (int j = 0; j < 4; ++j) {
                const int rl = wave * 32 + j * 8 + r8;
                *(bf16x8*)&Asm[cb][rl * 64 + wswz] = cvt8(apre[j][0], apre[j][1]);
            }
        }
        if (BF32) {
#pragma unroll
            for (int j = 0; j < 4; ++j) {
                const int rl = wave * 32 + j * 8 + r8;
                *(bf16x8*)&Bsm[cb][rl * 64 + wswz] = cvt8(bpre[j][0], bpre[j][1]);
            }
        }
        __syncthreads();     // drains async16 into buf cb + ds_writes; last reads of buf cb^1 done
        // issue next-tile stage into buf cb^1 / regs — overlaps this step's MFMA
        if (it < 7) {
            const int ktn = (it + 1) * 64;
#pragma unroll
            for (int j = 0; j < 4; ++j) {
                const int rl = wave * 32 + j * 8 + r8;
                if (AF32) {
                    const float* s = Af + (size_t)(m0 + rl) * 512 + ktn + c8;
                    apre[j][0] = *(const float4*)s; apre[j][1] = *(const float4*)(s + 4);
                } else {
                    async16(Ab + (size_t)(m0 + rl) * 512 + ktn + c8,
                            &Asm[cb ^ 1][(wave * 32 + j * 8) * 64]);
                }
                if (BF32) {
                    const float* s = Bf + (size_t)(n0 + rl) * 512 + ktn + c8;
                    bpre[j][0] = *(const float4*)s; bpre[j][1] = *(const float4*)(s + 4);
                } else {
                    async16(Bb + (size_t)(n0 + rl) * 512 + ktn + c8,
                            &Bsm[cb ^ 1][(wave * 32 + j * 8) * 64]);
                }
            }
        }
        // compute from buf cb
        for (int ks = 0; ks < 2; ++ks) {
            bf16x8 af[4];
            for (int mt = 0; mt < 4; ++mt)
                af[mt] = *(const bf16x8*)&Asm[cb][(mrow0 + mt * 16 + l16) * 64 + ((ks * 4 + quad) ^ swz) * 8];
            for (int nt = 0; nt < 4; ++nt) {
                bf16x8 bf = *(const bf16x8*)&Bsm[cb][(ncol0 + nt * 16 + l16) * 64 + ((ks * 4 + quad) ^ swz) * 8];
                for (int mt = 0; mt < 4; ++mt)
                    acc[mt][nt] = mfma_k32(af[mt], bf, acc[mt][nt]);
            }
        }
    }

    if (MODE == 0) {
        bf16_t* out = (bf16_t*)outp;
        for (int nt = 0; nt < 4; ++nt) {
            int e = n0 + ncol0 + nt * 16 + l16;
            int h = e >> 6, el = e & 63;
            for (int mt = 0; mt < 4; ++mt)
                for (int r = 0; r < 4; ++r) {
                    int row = m0 + mrow0 + mt * 16 + quad * 4 + r;   // b*4096+s
                    int b = row >> 12, s = row & 4095;
                    int elp = (((el >> 3) ^ (row & 7)) << 3) | (el & 7);
                    out[(((size_t)(b * 8 + h)) * 4096 + s) * 64 + elp] = (bf16_t)acc[mt][nt][r];
                }
        }
    } else {
        bf16_t* out = (bf16_t*)outp;
        for (int nt = 0; nt < 4; ++nt) {
            int s_g = n0 + ncol0 + nt * 16 + l16;
            int b = s_g >> 12;
            int sbase = (s_g & 4095) & ~63;
            int f = 16 * ((l16 >> 2) & 3) + 4 * nt + (l16 & 3);
            for (int mt = 0; mt < 4; ++mt)
                for (int r = 0; r < 4; ++r) {
                    int e_g = m0 + mrow0 + mt * 16 + quad * 4 + r;
                    int h = e_g >> 6, el = e_g & 63;
                    int col = sbase | ((((f >> 3) ^ (e_g & 7)) & 7) << 3) | (f & 7);
                    out[(((size_t)(b * 8 + h)) * 64 + el) * 4096 + col] = (bf16_t)acc[mt][nt][r];
                }
        }
    }
}

// grid (256,1,3); XCD-sibling swizzle: same-A-stripe blocks (4 y's) get ids
// 8 apart -> same XCD round-robin -> stripe L2-served.
__global__ __launch_bounds__(256, 2) void proj_fused(const float* __restrict__ q,
                                                     const float* __restrict__ k,
                                                     const float* __restrict__ v,
                                                     const bf16_t* __restrict__ Wc,
                                                     bf16_t* __restrict__ qh,
                                                     bf16_t* __restrict__ kh,
                                                     bf16_t* __restrict__ vh) {
    const int f = blockIdx.x;
    const int y = (f >> 3) & 3;
    const int x = (f & 7) | ((f >> 5) << 3);
    const int z = blockIdx.z;
    const bf16_t* W = Wc + (size_t)z * 262144;
    if (z == 0)
        gemm128_dbuf<0, 1, 0>(nullptr, q, W, nullptr, qh, x * 128, y * 128);
    else if (z == 1)
        gemm128_dbuf<0, 1, 0>(nullptr, k, W, nullptr, kh, x * 128, y * 128);
    else
        gemm128_dbuf<1, 0, 1>(W, nullptr, nullptr, v, vh, y * 128, x * 128);
}

// ---------------------------------------------------------------------------
// Final GEMM, double-buffered like proj: fused z-combine + softmax
// normalization rides the A reg-prefetch (Op/L loads for kt+1 issued under
// kt's MFMA); B = pre-converted bf16 Wo via async16 dbuf. XCD swizzle.
// ---------------------------------------------------------------------------
__global__ __launch_bounds__(256, 2) void gemm_final(const bf16_t* __restrict__ Op,
                                                     const float* __restrict__ Lp,
                                                     const bf16_t* __restrict__ B,
                                                     float* __restrict__ out) {
    __shared__ __bf16 Asm[2][128 * 64];
    __shared__ __bf16 Bsm[2][128 * 64];
    const int fb = blockIdx.x;
    const int m0 = ((fb & 7) | ((fb >> 5) << 3)) * 128;
    const int n0 = ((fb >> 3) & 3) * 128;
    const int tid  = threadIdx.x;
    const int wave = tid >> 6;
    const int lane = tid & 63;
    const int quad = lane >> 4;
    const int l16  = lane & 15;
    const int swz  = l16 & 7;
    const int r8 = lane >> 3;
    const int c8 = (lane & 7) * 8;
    const int mrow0 = (wave & 1) * 64;
    const int ncol0 = (wave >> 1) * 64;
    const int wswz = ((lane & 7) ^ r8) << 3;

    f32x4 acc[4][4];
    for (int i = 0; i < 4; ++i)
        for (int j = 0; j < 4; ++j) acc[i][j] = (f32x4){0.f, 0.f, 0.f, 0.f};

    bf16x8 oa0[4], oa1[4];
    float oinv[4];

    // prologue: kt=0 (h=0)
#pragma unroll
    for (int j = 0; j < 4; ++j) {
        const int rl = wave * 32 + j * 8 + r8;
        const int row = m0 + rl;
        const int b = row >> 12, sp = row & 4095;
        const size_t lidx = (size_t)(b * 8) * 4096 + sp;
        oa0[j] = *(const bf16x8*)(Op + lidx * 64 + c8);
        oa1[j] = *(const bf16x8*)(Op + 4194304 + lidx * 64 + c8);
        oinv[j] = 1.0f / (Lp[lidx] + Lp[65536 + lidx]);
        async16(B + (size_t)(n0 + rl) * 512 + c8, &Bsm[0][(wave * 32 + j * 8) * 64]);
    }

    for (int it = 0; it < 8; ++it) {
        const int cb = it & 1;
#pragma unroll
        for (int j = 0; j < 4; ++j) {
            const int rl = wave * 32 + j * 8 + r8;
            bf16x8 w;
            for (int i = 0; i < 8; ++i)
                w[i] = (bf16_t)(((float)oa0[j][i] + (float)oa1[j][i]) * oinv[j]);
            *(bf16x8*)&Asm[cb][rl * 64 + wswz] = w;
        }
        __syncthreads();
        if (it < 7) {
            const int hn = it + 1;
            const int ktn = hn * 64;
#pragma unroll
            for (int j = 0; j < 4; ++j) {
                const int rl = wave * 32 + j * 8 + r8;
                const int row = m0 + rl;
                const int b = row >> 12, sp = row & 4095;
                const size_t lidx = (size_t)(b * 8 + hn) * 4096 + sp;
                oa0[j] = *(const bf16x8*)(Op + lidx * 64 + c8);
                oa1[j] = *(const bf16x8*)(Op + 4194304 + lidx * 64 + c8);
                oinv[j] = 1.0f / (Lp[lidx] + Lp[65536 + lidx]);
                async16(B + (size_t)(n0 + rl) * 512 + ktn + c8,
                        &Bsm[cb ^ 1][(wave * 32 + j * 8) * 64]);
            }
        }
        for (int ks = 0; ks < 2; ++ks) {
            bf16x8 af[4];
            for (int mt = 0; mt < 4; ++mt)
                af[mt] = *(const bf16x8*)&Asm[cb][(mrow0 + mt * 16 + l16) * 64 + ((ks * 4 + quad) ^ swz) * 8];
            for (int nt = 0; nt < 4; ++nt) {
                bf16x8 bf = *(const bf16x8*)&Bsm[cb][(ncol0 + nt * 16 + l16) * 64 + ((ks * 4 + quad) ^ swz) * 8];
                for (int mt = 0; mt < 4; ++mt)
                    acc[mt][nt] = mfma_k32(af[mt], bf, acc[mt][nt]);
            }
        }
    }

    for (int nt = 0; nt < 4; ++nt) {
        int n = n0 + ncol0 + nt * 16 + l16;
        for (int mt = 0; mt < 4; ++mt)
            for (int r = 0; r < 4; ++r) {
                int row = m0 + mrow0 + mt * 16 + quad * 4 + r;
                out[(size_t)row * 512 + n] = acc[mt][nt][r];
            }
    }
}

// ---------------------------------------------------------------------------
// Causal flash attention v7 (verbatim R2/R5 winner, 62.2-62.6us): FROZEN.
// Four restructure attempts failed; root cause: 64 VGPR + 64 AGPR = the
// full 128-reg budget at (256,4) — any added live state spills.
// ---------------------------------------------------------------------------
__global__ __launch_bounds__(256, 4) void attn_kernel(const bf16_t* __restrict__ qh,
                                                      const bf16_t* __restrict__ kh,
                                                      const bf16_t* __restrict__ vh,
                                                      bf16_t* __restrict__ Opart,
                                                      float* __restrict__ Lpart) {
    __shared__ __bf16 SM[16384];            // 32 KB: K panels [2][64][64] + V panels
    __bf16* KSM = &SM[0];
    __bf16* VSM = &SM[8192];
    float* Osc = (float*)SM;                // 16.6 KB leg-end scratch [q][65]
    float* Lsc = (float*)&SM[8320];         // 256 B lsum scratch [q] (byte 16640)

    const int id   = blockIdx.x;
    const int bh   = ((id & 7) << 1) | ((id >> 3) & 1);   // XCD-grouped
    const int pair = (id >> 4) & 31;
    const int z    = (id >> 9) & 1;

    const int tid  = threadIdx.x;
    const int wave = tid >> 6;
    const int g2   = wave >> 1;             // K-panel parity within step
    const int wl   = wave & 1;              // query half
    const int lane = tid & 63;
    const int quad = lane >> 4;
    const int l16  = lane & 15;
    const int swz  = l16 & 7;
    const size_t base = (size_t)bh * 4096 * 64;
    const int r8 = lane >> 3;
    const int c8 = (lane & 7) * 8;

    bf16_t* Op = Opart + (size_t)z * 4194304;
    float*  Lp = Lpart + z * 65536;

    for (int leg = 0; leg < 2; ++leg) {
        const int qt = leg ? (63 - pair) : pair;
        const int q0 = qt * 64;

        bf16x8 qf[2][2];
        for (int g = 0; g < 2; ++g) {
            const bf16_t* qp = qh + base + (size_t)(q0 + wl * 32 + g * 16 + l16) * 64;
            qf[g][0] = *(const bf16x8*)(qp + ((quad ^ swz) * 8));
            qf[g][1] = *(const bf16x8*)(qp + (((4 + quad) ^ swz) * 8));
        }

        f32x4 o[2][4];
        for (int g = 0; g < 2; ++g)
            for (int i = 0; i < 4; ++i) o[g][i] = (f32x4){0.f, 0.f, 0.f, 0.f};
        float lsum[2] = {0.f, 0.f};

        const int S  = (qt + 2) >> 1;       // total 128-key steps of this leg
        const int Sh = (S + 1) >> 1;        // z=0 takes [0,Sh), z=1 takes [Sh,S)
        const int it0 = z ? Sh : 0;
        const int it1 = z ? S : Sh;

        for (int it = it0; it < it1; ++it) {
            const int j0 = it * 128;
            __syncthreads();
            for (int p = 0; p < 2; ++p)
                for (int j = 0; j < 2; ++j) {
                    int row = wave * 16 + j * 8 + r8;
                    async16(kh + base + (size_t)(j0 + p * 64 + row) * 64 + c8,
                            KSM + (p * 64 + wave * 16 + j * 8) * 64);
                    async16(vh + (size_t)(bh * 64 + row) * 4096 + j0 + p * 64 + c8,
                            VSM + (p * 64 + wave * 16 + j * 8) * 64);
                }
            __syncthreads();

            const int pp = g2;
            const int koff = j0 + pp * 64 - q0;
            if (koff > wl * 32 + 31) continue;     // fully masked for this wave

            // S^T = K·Q^T (C: col=query=l16, row=key=nt*16+quad*4+r)
            f32x4 st[2][4];
            for (int nt = 0; nt < 4; ++nt) {
                const __bf16* kr = KSM + (pp * 64 + nt * 16 + l16) * 64;
                bf16x8 kf0 = *(const bf16x8*)(kr + ((quad ^ swz) * 8));
                bf16x8 kf1 = *(const bf16x8*)(kr + (((4 + quad) ^ swz) * 8));
                for (int g = 0; g < 2; ++g) {
                    f32x4 zz = (f32x4){0.f, 0.f, 0.f, 0.f};
                    zz = mfma_k32(kf0, qf[g][0], zz);
                    zz = mfma_k32(kf1, qf[g][1], zz);
                    st[g][nt] = zz;
                }
            }

            // fixed-base softmax: p = exp2(st)
            bf16x4 pf[2][4];
            for (int g = 0; g < 2; ++g) {
                const int qb = wl * 32 + g * 16;
                if (koff + 63 <= qb) {
                    for (int nt = 0; nt < 4; ++nt)
                        for (int r = 0; r < 4; ++r) {
                            float p = fast_exp2(st[g][nt][r]);
                            lsum[g] += p;
                            pf[g][nt][r] = (bf16_t)p;
                        }
                } else {
                    const int qrow = qb + l16;
                    for (int nt = 0; nt < 4; ++nt)
                        for (int r = 0; r < 4; ++r) {
                            int key = nt * 16 + quad * 4 + r;
                            float p = (key + koff <= qrow) ? fast_exp2(st[g][nt][r]) : 0.f;
                            lsum[g] += p;
                            pf[g][nt][r] = (bf16_t)p;
                        }
                }
            }

            // O += P·V (P register-resident)
            for (int dt = 0; dt < 4; ++dt)
                for (int kt2 = 0; kt2 < 2; ++kt2) {
                    bf16x8 vf = *(const bf16x8*)&VSM[(pp * 64 + dt * 16 + l16) * 64 + (((2 * quad + kt2) ^ swz) * 8)];
                    bf16x4 vlo = {vf[0], vf[1], vf[2], vf[3]};
                    bf16x4 vhi = {vf[4], vf[5], vf[6], vf[7]};
                    for (int g = 0; g < 2; ++g) {
                        o[g][dt] = mfma_k16(pf[g][2 * kt2], vlo, o[g][dt]);
                        o[g][dt] = mfma_k16(pf[g][2 * kt2 + 1], vhi, o[g][dt]);
                    }
                }
        }

        // ---- combine K-parity partials within block, write leg partials ----
        __syncthreads();                    // all K/V LDS reads done
        if (g2 == 1) {
            for (int g = 0; g < 2; ++g) {
                float ls = lsum[g];
                ls += __shfl_xor(ls, 16);
                ls += __shfl_xor(ls, 32);
                const int qb = wl * 32 + g * 16;
                Lsc[qb + l16] = ls;
                for (int dt = 0; dt < 4; ++dt)
                    for (int r = 0; r < 4; ++r)
                        Osc[(qb + quad * 4 + r) * 65 + dt * 16 + l16] = o[g][dt][r];
            }
        }
        __syncthreads();
        if (g2 == 0) {
            for (int g = 0; g < 2; ++g) {
                float ls = lsum[g];
                ls += __shfl_xor(ls, 16);
                ls += __shfl_xor(ls, 32);
                const int qb = wl * 32 + g * 16;
                ls += Lsc[qb + l16];
                Lsc[qb + l16] = ls;         // total lsum for this z
                for (int dt = 0; dt < 4; ++dt)
                    for (int r = 0; r < 4; ++r) {
                        int idx = (qb + quad * 4 + r) * 65 + dt * 16 + l16;
                        Osc[idx] = o[g][dt][r] + Osc[idx];
                    }
            }
        }
        __syncthreads();
        // repack: contiguous bf16 partial rows [q][e] + fp32 lsum
        {
            const int q  = tid >> 2;
            const int e0 = (tid & 3) * 16;
            bf16x8 w0, w1;
            for (int i = 0; i < 8; ++i) {
                w0[i] = (bf16_t)Osc[q * 65 + e0 + i];
                w1[i] = (bf16_t)Osc[q * 65 + e0 + 8 + i];
            }
            size_t slot = ((size_t)(bh * 64 + qt)) * 4096 + q * 64 + e0;
            *(bf16x8*)&Op[slot]     = w0;
            *(bf16x8*)&Op[slot + 8] = w1;
            if (tid < 64) Lp[(bh * 64 + qt) * 64 + tid] = Lsc[tid];
        }
        // next leg's first __syncthreads() protects Osc/Lsc reuse
    }
}

// ---------------------------------------------------------------------------
extern "C" void kernel_launch(void* const* d_in, const int* in_sizes, int n_in,
                              void* d_out, int out_size, void* d_ws, size_t ws_size,
                              hipStream_t stream) {
    const float* q  = (const float*)d_in[0];
    const float* k  = (const float*)d_in[1];
    const float* v  = (const float*)d_in[2];
    const float* Wq = (const float*)d_in[3];
    const float* Wk = (const float*)d_in[4];
    const float* Wv = (const float*)d_in[5];
    const float* Wo = (const float*)d_in[6];
    float* out = (float*)d_out;

    bf16_t* ws = (bf16_t*)d_ws;
    const size_t R = (size_t)8192 * 512;   // 4.19M elems = 8.39 MB per region
    bf16_t* opart = ws + R;          // R1+R2: Opart z0/z1
    bf16_t* vh = ws + 3 * R;         // R3: V^T heads
    bf16_t* Wc = ws + 4 * R;         // +2 MB bf16 weights (Wq pre-scaled)
    float*  Lp = (float*)(ws + 4 * R + 1048576);  // +0.5 MB lsum partials
    bf16_t* qh = (bf16_t*)d_out;     // qh/kh in d_out, dead before final GEMM
    bf16_t* kh = (bf16_t*)d_out + R;

    cvt_W<<<dim3(512), dim3(256), 0, stream>>>(Wq, Wk, Wv, Wo, Wc);
    proj_fused<<<dim3(256, 1, 3), dim3(256), 0, stream>>>(q, k, v, Wc, qh, kh, vh);
    attn_kernel<<<dim3(1024), dim3(256), 0, stream>>>(qh, kh, vh, opart, Lp);
    gemm_final<<<dim3(256), dim3(256), 0, stream>>>(opart, Lp, Wc + 3 * 262144, out);
}

// Round 11
// 238.614 us; speedup vs baseline: 1.4221x; 1.0283x over previous
//
#include <hip/hip_runtime.h>
#include <hip/hip_bf16.h>
#include <math.h>

typedef __bf16 bf16_t;
typedef __bf16 bf16x8 __attribute__((ext_vector_type(8)));
typedef __bf16 bf16x4 __attribute__((ext_vector_type(4)));
typedef short short4v __attribute__((ext_vector_type(4)));
typedef float f32x4 __attribute__((ext_vector_type(4)));

__device__ __forceinline__ f32x4 mfma_k32(bf16x8 a, bf16x8 b, f32x4 c) {
    return __builtin_amdgcn_mfma_f32_16x16x32_bf16(a, b, c, 0, 0, 0);
}

__device__ __forceinline__ f32x4 mfma_k16(bf16x4 a, bf16x4 b, f32x4 c) {
#if __has_builtin(__builtin_amdgcn_mfma_f32_16x16x16_bf16)
    return __builtin_amdgcn_mfma_f32_16x16x16_bf16(a, b, c, 0, 0, 0);
#elif __has_builtin(__builtin_amdgcn_mfma_f32_16x16x16bf16_1k)
    short4v as, bs;
    __builtin_memcpy(&as, &a, 8);
    __builtin_memcpy(&bs, &b, 8);
    return __builtin_amdgcn_mfma_f32_16x16x16bf16_1k(as, bs, c, 0, 0, 0);
#else
    f32x4 d = c;
    asm volatile("v_mfma_f32_16x16x16_bf16 %0, %1, %2, %0" : "+v"(d) : "v"(a), "v"(b));
    return d;
#endif
}

// raw v_exp_f32 (exp2): avoid OCML guard code around exp2f
__device__ __forceinline__ float fast_exp2(float x) {
#if __has_builtin(__builtin_amdgcn_exp2f)
    return __builtin_amdgcn_exp2f(x);
#else
    float r;
    asm("v_exp_f32 %0, %1" : "=v"(r) : "v"(x));
    return r;
#endif
}

// async global->LDS, 16B/lane; LDS dest = wave-uniform base + lane*16
__device__ __forceinline__ void async16(const bf16_t* g, __bf16* l) {
    __builtin_amdgcn_global_load_lds(
        (const __attribute__((address_space(1))) void*)g,
        (__attribute__((address_space(3))) void*)l, 16, 0, 0);
}

// XOR-swizzle: 16B chunks within each 64-col group, keyed by row&7 (global-side)
__device__ __forceinline__ int swz_col(int col, int row) {
    return (col & ~63) | ((((col >> 3) & 7) ^ (row & 7)) << 3) | (col & 7);
}

__device__ __forceinline__ bf16x8 cvt8(float4 a, float4 b) {
    bf16x8 w;
    w[0]=(__bf16)a.x; w[1]=(__bf16)a.y; w[2]=(__bf16)a.z; w[3]=(__bf16)a.w;
    w[4]=(__bf16)b.x; w[5]=(__bf16)b.y; w[6]=(__bf16)b.z; w[7]=(__bf16)b.w;
    return w;
}

// ---------------------------------------------------------------------------
// fp32 -> bf16 swizzled convert, W only (R7 lesson: keep this kernel).
// ---------------------------------------------------------------------------
__global__ __launch_bounds__(256) void cvt_W(const float* __restrict__ Wq,
                                             const float* __restrict__ Wk,
                                             const float* __restrict__ Wv,
                                             const float* __restrict__ Wo,
                                             bf16_t* __restrict__ Wc) {
    const int b2 = blockIdx.x;
    const int m = b2 >> 7;                   // which W
    const float* src = m == 0 ? Wq : m == 1 ? Wk : m == 2 ? Wv : Wo;
    const float sc = (m == 0) ? 0.125f * 1.44269504088896f : 1.0f;
    size_t i = ((size_t)(b2 & 127) * 256 + threadIdx.x) * 8;
    int row = (int)(i >> 9), col = (int)(i & 511);
    float4 a0 = *(const float4*)(src + i), a1 = *(const float4*)(src + i + 4);
    bf16x8 o;
    o[0]=(__bf16)(a0.x*sc); o[1]=(__bf16)(a0.y*sc); o[2]=(__bf16)(a0.z*sc); o[3]=(__bf16)(a0.w*sc);
    o[4]=(__bf16)(a1.x*sc); o[5]=(__bf16)(a1.y*sc); o[6]=(__bf16)(a1.z*sc); o[7]=(__bf16)(a1.w*sc);
    *(bf16x8*)(Wc + (size_t)m * 262144 + (size_t)row * 512 + swz_col(col, row)) = o;
}

// ---------------------------------------------------------------------------
// 128x128-tile NT GEMM (R5's proven single-buffered body), LDS passed in by
// POINTER from the kernel. R10 finding: function-scope __shared__ arrays in
// template instantiations are NOT merged by the compiler — proj_fused's two
// instantiations each allocated their own tiles (R10 dbuf: 2x64KB=128KB ->
// 1 block/CU, MfmaUtil 5%; R5 single-buf: 2x32KB=64KB -> 2 blocks/CU,
// silently halving occupancy all session). Kernel-scope arrays fix it: one
// 32KB allocation -> 4-5 blocks/CU.
//   AF32/BF32 = 1: fp32 operand; reg-load 32B/lane, cvt, Latin-square-swizzled
//     ds_write_b128. 0: pre-swizzled bf16; global_load_lds direct.
// ---------------------------------------------------------------------------
template<int MODE, int AF32, int BF32>
__device__ __forceinline__ void gemm128_body(__bf16* __restrict__ Asm,
                                             __bf16* __restrict__ Bsm,
                                             const bf16_t* __restrict__ Ab,
                                             const float* __restrict__ Af,
                                             const bf16_t* __restrict__ Bb,
                                             const float* __restrict__ Bf,
                                             void* __restrict__ outp,
                                             int m0, int n0) {
    const int tid  = threadIdx.x;
    const int wave = tid >> 6;
    const int lane = tid & 63;
    const int quad = lane >> 4;
    const int l16  = lane & 15;
    const int swz  = l16 & 7;
    const int r8 = lane >> 3;
    const int c8 = (lane & 7) * 8;
    const int mrow0 = (wave & 1) * 64;
    const int ncol0 = (wave >> 1) * 64;

    f32x4 acc[4][4];
    for (int i = 0; i < 4; ++i)
        for (int j = 0; j < 4; ++j) acc[i][j] = (f32x4){0.f, 0.f, 0.f, 0.f};

    for (int kt = 0; kt < 512; kt += 64) {
        __syncthreads();
        for (int j = 0; j < 4; ++j) {
            const int rl = wave * 32 + j * 8 + r8;
            if (AF32) {
                const float* s = Af + (size_t)(m0 + rl) * 512 + kt + c8;
                float4 v0 = *(const float4*)s, v1 = *(const float4*)(s + 4);
                *(bf16x8*)&Asm[rl * 64 + (((lane & 7) ^ r8) << 3)] = cvt8(v0, v1);
            } else {
                async16(Ab + (size_t)(m0 + rl) * 512 + kt + c8,
                        &Asm[(wave * 32 + j * 8) * 64]);
            }
            if (BF32) {
                const float* s = Bf + (size_t)(n0 + rl) * 512 + kt + c8;
                float4 v0 = *(const float4*)s, v1 = *(const float4*)(s + 4);
                *(bf16x8*)&Bsm[rl * 64 + (((lane & 7) ^ r8) << 3)] = cvt8(v0, v1);
            } else {
                async16(Bb + (size_t)(n0 + rl) * 512 + kt + c8,
                        &Bsm[(wave * 32 + j * 8) * 64]);
            }
        }
        __syncthreads();

        for (int ks = 0; ks < 2; ++ks) {
            bf16x8 af[4];
            for (int mt = 0; mt < 4; ++mt)
                af[mt] = *(const bf16x8*)&Asm[(mrow0 + mt * 16 + l16) * 64 + ((ks * 4 + quad) ^ swz) * 8];
            for (int nt = 0; nt < 4; ++nt) {
                bf16x8 bf = *(const bf16x8*)&Bsm[(ncol0 + nt * 16 + l16) * 64 + ((ks * 4 + quad) ^ swz) * 8];
                for (int mt = 0; mt < 4; ++mt)
                    acc[mt][nt] = mfma_k32(af[mt], bf, acc[mt][nt]);
            }
        }
    }

    if (MODE == 0) {
        bf16_t* out = (bf16_t*)outp;
        for (int nt = 0; nt < 4; ++nt) {
            int e = n0 + ncol0 + nt * 16 + l16;
            int h = e >> 6, el = e & 63;
            for (int mt = 0; mt < 4; ++mt)
                for (int r = 0; r < 4; ++r) {
                    int row = m0 + mrow0 + mt * 16 + quad * 4 + r;   // b*4096+s
                    int b = row >> 12, s = row & 4095;
                    int elp = (((el >> 3) ^ (row & 7)) << 3) | (el & 7);
                    out[(((size_t)(b * 8 + h)) * 4096 + s) * 64 + elp] = (bf16_t)acc[mt][nt][r];
                }
        }
    } else {
        bf16_t* out = (bf16_t*)outp;
        for (int nt = 0; nt < 4; ++nt) {
            int s_g = n0 + ncol0 + nt * 16 + l16;
            int b = s_g >> 12;
            int sbase = (s_g & 4095) & ~63;
            int f = 16 * ((l16 >> 2) & 3) + 4 * nt + (l16 & 3);
            for (int mt = 0; mt < 4; ++mt)
                for (int r = 0; r < 4; ++r) {
                    int e_g = m0 + mrow0 + mt * 16 + quad * 4 + r;
                    int h = e_g >> 6, el = e_g & 63;
                    int col = sbase | ((((f >> 3) ^ (e_g & 7)) & 7) << 3) | (f & 7);
                    out[(((size_t)(b * 8 + h)) * 64 + el) * 4096 + col] = (bf16_t)acc[mt][nt][r];
                }
        }
    }
}

// grid (256,1,3); XCD-sibling swizzle: same-A-stripe blocks (4 y's) get ids
// 8 apart -> same XCD round-robin -> stripe L2-served.
// SINGLE kernel-scope 32KB LDS shared by all template instantiations.
__global__ __launch_bounds__(256) void proj_fused(const float* __restrict__ q,
                                                  const float* __restrict__ k,
                                                  const float* __restrict__ v,
                                                  const bf16_t* __restrict__ Wc,
                                                  bf16_t* __restrict__ qh,
                                                  bf16_t* __restrict__ kh,
                                                  bf16_t* __restrict__ vh) {
    __shared__ __bf16 Asm[128 * 64];
    __shared__ __bf16 Bsm[128 * 64];
    const int f = blockIdx.x;
    const int y = (f >> 3) & 3;
    const int x = (f & 7) | ((f >> 5) << 3);
    const int z = blockIdx.z;
    const bf16_t* W = Wc + (size_t)z * 262144;
    if (z == 0)
        gemm128_body<0, 1, 0>(Asm, Bsm, nullptr, q, W, nullptr, qh, x * 128, y * 128);
    else if (z == 1)
        gemm128_body<0, 1, 0>(Asm, Bsm, nullptr, k, W, nullptr, kh, x * 128, y * 128);
    else
        gemm128_body<1, 0, 1>(Asm, Bsm, W, nullptr, nullptr, v, vh, y * 128, x * 128);
}

// ---------------------------------------------------------------------------
// Final GEMM (R5 version): fused z-combine + softmax normalization in
// A-staging, B = pre-converted bf16 Wo via async16, XCD swizzle. Single
// instantiation -> no LDS duplication (32 KB).
// ---------------------------------------------------------------------------
__global__ __launch_bounds__(256) void gemm_final(const bf16_t* __restrict__ Op,
                                                  const float* __restrict__ Lp,
                                                  const bf16_t* __restrict__ B,
                                                  float* __restrict__ out) {
    __shared__ __bf16 Asm[128 * 64];
    __shared__ __bf16 Bsm[128 * 64];
    const int fb = blockIdx.x;
    const int m0 = ((fb & 7) | ((fb >> 5) << 3)) * 128;
    const int n0 = ((fb >> 3) & 3) * 128;
    const int tid  = threadIdx.x;
    const int wave = tid >> 6;
    const int lane = tid & 63;
    const int quad = lane >> 4;
    const int l16  = lane & 15;
    const int swz  = l16 & 7;
    const int r8 = lane >> 3;
    const int c8 = (lane & 7) * 8;
    const int mrow0 = (wave & 1) * 64;
    const int ncol0 = (wave >> 1) * 64;

    f32x4 acc[4][4];
    for (int i = 0; i < 4; ++i)
        for (int j = 0; j < 4; ++j) acc[i][j] = (f32x4){0.f, 0.f, 0.f, 0.f};

    for (int kt = 0; kt < 512; kt += 64) {
        const int h = kt >> 6;
        __syncthreads();
        for (int j = 0; j < 4; ++j)
            async16(B + (size_t)(n0 + wave * 32 + j * 8 + r8) * 512 + kt + c8,
                    &Bsm[(wave * 32 + j * 8) * 64]);
        for (int j = 0; j < 4; ++j) {
            const int rl  = wave * 32 + j * 8 + r8;
            const int row = m0 + rl;                 // b*4096 + s
            const int b   = row >> 12, sp = row & 4095;
            const size_t lidx = (size_t)(b * 8 + h) * 4096 + sp;
            bf16x8 a0 = *(const bf16x8*)(Op + lidx * 64 + c8);
            bf16x8 a1 = *(const bf16x8*)(Op + 4194304 + lidx * 64 + c8);
            float inv = 1.0f / (Lp[lidx] + Lp[65536 + lidx]);
            bf16x8 w;
            for (int i = 0; i < 8; ++i)
                w[i] = (bf16_t)(((float)a0[i] + (float)a1[i]) * inv);
            *(bf16x8*)&Asm[rl * 64 + (((lane & 7) ^ r8) << 3)] = w;
        }
        __syncthreads();

        for (int ks = 0; ks < 2; ++ks) {
            bf16x8 af[4];
            for (int mt = 0; mt < 4; ++mt)
                af[mt] = *(const bf16x8*)&Asm[(mrow0 + mt * 16 + l16) * 64 + ((ks * 4 + quad) ^ swz) * 8];
            for (int nt = 0; nt < 4; ++nt) {
                bf16x8 bf = *(const bf16x8*)&Bsm[(ncol0 + nt * 16 + l16) * 64 + ((ks * 4 + quad) ^ swz) * 8];
                for (int mt = 0; mt < 4; ++mt)
                    acc[mt][nt] = mfma_k32(af[mt], bf, acc[mt][nt]);
            }
        }
    }

    for (int nt = 0; nt < 4; ++nt) {
        int n = n0 + ncol0 + nt * 16 + l16;
        for (int mt = 0; mt < 4; ++mt)
            for (int r = 0; r < 4; ++r) {
                int row = m0 + mrow0 + mt * 16 + quad * 4 + r;
                out[(size_t)row * 512 + n] = acc[mt][nt][r];
            }
    }
}

// ---------------------------------------------------------------------------
// Causal flash attention v7 (verbatim R2/R5 winner, 62.2-62.6us): FROZEN.
// Four restructure attempts failed; root cause: 64 VGPR + 64 AGPR = the
// full 128-reg budget at (256,4) — any added live state spills.
// ---------------------------------------------------------------------------
__global__ __launch_bounds__(256, 4) void attn_kernel(const bf16_t* __restrict__ qh,
                                                      const bf16_t* __restrict__ kh,
                                                      const bf16_t* __restrict__ vh,
                                                      bf16_t* __restrict__ Opart,
                                                      float* __restrict__ Lpart) {
    __shared__ __bf16 SM[16384];            // 32 KB: K panels [2][64][64] + V panels
    __bf16* KSM = &SM[0];
    __bf16* VSM = &SM[8192];
    float* Osc = (float*)SM;                // 16.6 KB leg-end scratch [q][65]
    float* Lsc = (float*)&SM[8320];         // 256 B lsum scratch [q] (byte 16640)

    const int id   = blockIdx.x;
    const int bh   = ((id & 7) << 1) | ((id >> 3) & 1);   // XCD-grouped
    const int pair = (id >> 4) & 31;
    const int z    = (id >> 9) & 1;

    const int tid  = threadIdx.x;
    const int wave = tid >> 6;
    const int g2   = wave >> 1;             // K-panel parity within step
    const int wl   = wave & 1;              // query half
    const int lane = tid & 63;
    const int quad = lane >> 4;
    const int l16  = lane & 15;
    const int swz  = l16 & 7;
    const size_t base = (size_t)bh * 4096 * 64;
    const int r8 = lane >> 3;
    const int c8 = (lane & 7) * 8;

    bf16_t* Op = Opart + (size_t)z * 4194304;
    float*  Lp = Lpart + z * 65536;

    for (int leg = 0; leg < 2; ++leg) {
        const int qt = leg ? (63 - pair) : pair;
        const int q0 = qt * 64;

        bf16x8 qf[2][2];
        for (int g = 0; g < 2; ++g) {
            const bf16_t* qp = qh + base + (size_t)(q0 + wl * 32 + g * 16 + l16) * 64;
            qf[g][0] = *(const bf16x8*)(qp + ((quad ^ swz) * 8));
            qf[g][1] = *(const bf16x8*)(qp + (((4 + quad) ^ swz) * 8));
        }

        f32x4 o[2][4];
        for (int g = 0; g < 2; ++g)
            for (int i = 0; i < 4; ++i) o[g][i] = (f32x4){0.f, 0.f, 0.f, 0.f};
        float lsum[2] = {0.f, 0.f};

        const int S  = (qt + 2) >> 1;       // total 128-key steps of this leg
        const int Sh = (S + 1) >> 1;        // z=0 takes [0,Sh), z=1 takes [Sh,S)
        const int it0 = z ? Sh : 0;
        const int it1 = z ? S : Sh;

        for (int it = it0; it < it1; ++it) {
            const int j0 = it * 128;
            __syncthreads();
            for (int p = 0; p < 2; ++p)
                for (int j = 0; j < 2; ++j) {
                    int row = wave * 16 + j * 8 + r8;
                    async16(kh + base + (size_t)(j0 + p * 64 + row) * 64 + c8,
                            KSM + (p * 64 + wave * 16 + j * 8) * 64);
                    async16(vh + (size_t)(bh * 64 + row) * 4096 + j0 + p * 64 + c8,
                            VSM + (p * 64 + wave * 16 + j * 8) * 64);
                }
            __syncthreads();

            const int pp = g2;
            const int koff = j0 + pp * 64 - q0;
            if (koff > wl * 32 + 31) continue;     // fully masked for this wave

            // S^T = K·Q^T (C: col=query=l16, row=key=nt*16+quad*4+r)
            f32x4 st[2][4];
            for (int nt = 0; nt < 4; ++nt) {
                const __bf16* kr = KSM + (pp * 64 + nt * 16 + l16) * 64;
                bf16x8 kf0 = *(const bf16x8*)(kr + ((quad ^ swz) * 8));
                bf16x8 kf1 = *(const bf16x8*)(kr + (((4 + quad) ^ swz) * 8));
                for (int g = 0; g < 2; ++g) {
                    f32x4 zz = (f32x4){0.f, 0.f, 0.f, 0.f};
                    zz = mfma_k32(kf0, qf[g][0], zz);
                    zz = mfma_k32(kf1, qf[g][1], zz);
                    st[g][nt] = zz;
                }
            }

            // fixed-base softmax: p = exp2(st)
            bf16x4 pf[2][4];
            for (int g = 0; g < 2; ++g) {
                const int qb = wl * 32 + g * 16;
                if (koff + 63 <= qb) {
                    for (int nt = 0; nt < 4; ++nt)
                        for (int r = 0; r < 4; ++r) {
                            float p = fast_exp2(st[g][nt][r]);
                            lsum[g] += p;
                            pf[g][nt][r] = (bf16_t)p;
                        }
                } else {
                    const int qrow = qb + l16;
                    for (int nt = 0; nt < 4; ++nt)
                        for (int r = 0; r < 4; ++r) {
                            int key = nt * 16 + quad * 4 + r;
                            float p = (key + koff <= qrow) ? fast_exp2(st[g][nt][r]) : 0.f;
                            lsum[g] += p;
                            pf[g][nt][r] = (bf16_t)p;
                        }
                }
            }

            // O += P·V (P register-resident)
            for (int dt = 0; dt < 4; ++dt)
                for (int kt2 = 0; kt2 < 2; ++kt2) {
                    bf16x8 vf = *(const bf16x8*)&VSM[(pp * 64 + dt * 16 + l16) * 64 + (((2 * quad + kt2) ^ swz) * 8)];
                    bf16x4 vlo = {vf[0], vf[1], vf[2], vf[3]};
                    bf16x4 vhi = {vf[4], vf[5], vf[6], vf[7]};
                    for (int g = 0; g < 2; ++g) {
                        o[g][dt] = mfma_k16(pf[g][2 * kt2], vlo, o[g][dt]);
                        o[g][dt] = mfma_k16(pf[g][2 * kt2 + 1], vhi, o[g][dt]);
                    }
                }
        }

        // ---- combine K-parity partials within block, write leg partials ----
        __syncthreads();                    // all K/V LDS reads done
        if (g2 == 1) {
            for (int g = 0; g < 2; ++g) {
                float ls = lsum[g];
                ls += __shfl_xor(ls, 16);
                ls += __shfl_xor(ls, 32);
                const int qb = wl * 32 + g * 16;
                Lsc[qb + l16] = ls;
                for (int dt = 0; dt < 4; ++dt)
                    for (int r = 0; r < 4; ++r)
                        Osc[(qb + quad * 4 + r) * 65 + dt * 16 + l16] = o[g][dt][r];
            }
        }
        __syncthreads();
        if (g2 == 0) {
            for (int g = 0; g < 2; ++g) {
                float ls = lsum[g];
                ls += __shfl_xor(ls, 16);
                ls += __shfl_xor(ls, 32);
                const int qb = wl * 32 + g * 16;
                ls += Lsc[qb + l16];
                Lsc[qb + l16] = ls;         // total lsum for this z
                for (int dt = 0; dt < 4; ++dt)
                    for (int r = 0; r < 4; ++r) {
                        int idx = (qb + quad * 4 + r) * 65 + dt * 16 + l16;
                        Osc[idx] = o[g][dt][r] + Osc[idx];
                    }
            }
        }
        __syncthreads();
        // repack: contiguous bf16 partial rows [q][e] + fp32 lsum
        {
            const int q  = tid >> 2;
            const int e0 = (tid & 3) * 16;
            bf16x8 w0, w1;
            for (int i = 0; i < 8; ++i) {
                w0[i] = (bf16_t)Osc[q * 65 + e0 + i];
                w1[i] = (bf16_t)Osc[q * 65 + e0 + 8 + i];
            }
            size_t slot = ((size_t)(bh * 64 + qt)) * 4096 + q * 64 + e0;
            *(bf16x8*)&Op[slot]     = w0;
            *(bf16x8*)&Op[slot + 8] = w1;
            if (tid < 64) Lp[(bh * 64 + qt) * 64 + tid] = Lsc[tid];
        }
        // next leg's first __syncthreads() protects Osc/Lsc reuse
    }
}

// ---------------------------------------------------------------------------
extern "C" void kernel_launch(void* const* d_in, const int* in_sizes, int n_in,
                              void* d_out, int out_size, void* d_ws, size_t ws_size,
                              hipStream_t stream) {
    const float* q  = (const float*)d_in[0];
    const float* k  = (const float*)d_in[1];
    const float* v  = (const float*)d_in[2];
    const float* Wq = (const float*)d_in[3];
    const float* Wk = (const float*)d_in[4];
    const float* Wv = (const float*)d_in[5];
    const float* Wo = (const float*)d_in[6];
    float* out = (float*)d_out;

    bf16_t* ws = (bf16_t*)d_ws;
    const size_t R = (size_t)8192 * 512;   // 4.19M elems = 8.39 MB per region
    bf16_t* opart = ws + R;          // R1+R2: Opart z0/z1
    bf16_t* vh = ws + 3 * R;         // R3: V^T heads
    bf16_t* Wc = ws + 4 * R;         // +2 MB bf16 weights (Wq pre-scaled)
    float*  Lp = (float*)(ws + 4 * R + 1048576);  // +0.5 MB lsum partials
    bf16_t* qh = (bf16_t*)d_out;     // qh/kh in d_out, dead before final GEMM
    bf16_t* kh = (bf16_t*)d_out + R;

    cvt_W<<<dim3(512), dim3(256), 0, stream>>>(Wq, Wk, Wv, Wo, Wc);
    proj_fused<<<dim3(256, 1, 3), dim3(256), 0, stream>>>(q, k, v, Wc, qh, kh, vh);
    attn_kernel<<<dim3(1024), dim3(256), 0, stream>>>(qh, kh, vh, opart, Lp);
    gemm_final<<<dim3(256), dim3(256), 0, stream>>>(opart, Lp, Wc + 3 * 262144, out);
}

// Round 12
// 233.509 us; speedup vs baseline: 1.4532x; 1.0219x over previous
//
#include <hip/hip_runtime.h>
#include <hip/hip_bf16.h>
#include <math.h>

typedef __bf16 bf16_t;
typedef __bf16 bf16x8 __attribute__((ext_vector_type(8)));
typedef __bf16 bf16x4 __attribute__((ext_vector_type(4)));
typedef short short4v __attribute__((ext_vector_type(4)));
typedef float f32x4 __attribute__((ext_vector_type(4)));

__device__ __forceinline__ f32x4 mfma_k32(bf16x8 a, bf16x8 b, f32x4 c) {
    return __builtin_amdgcn_mfma_f32_16x16x32_bf16(a, b, c, 0, 0, 0);
}

__device__ __forceinline__ f32x4 mfma_k16(bf16x4 a, bf16x4 b, f32x4 c) {
#if __has_builtin(__builtin_amdgcn_mfma_f32_16x16x16_bf16)
    return __builtin_amdgcn_mfma_f32_16x16x16_bf16(a, b, c, 0, 0, 0);
#elif __has_builtin(__builtin_amdgcn_mfma_f32_16x16x16bf16_1k)
    short4v as, bs;
    __builtin_memcpy(&as, &a, 8);
    __builtin_memcpy(&bs, &b, 8);
    return __builtin_amdgcn_mfma_f32_16x16x16bf16_1k(as, bs, c, 0, 0, 0);
#else
    f32x4 d = c;
    asm volatile("v_mfma_f32_16x16x16_bf16 %0, %1, %2, %0" : "+v"(d) : "v"(a), "v"(b));
    return d;
#endif
}

// raw v_exp_f32 (exp2): avoid OCML guard code around exp2f
__device__ __forceinline__ float fast_exp2(float x) {
#if __has_builtin(__builtin_amdgcn_exp2f)
    return __builtin_amdgcn_exp2f(x);
#else
    float r;
    asm("v_exp_f32 %0, %1" : "=v"(r) : "v"(x));
    return r;
#endif
}

// async global->LDS, 16B/lane; LDS dest = wave-uniform base + lane*16
__device__ __forceinline__ void async16(const bf16_t* g, __bf16* l) {
    __builtin_amdgcn_global_load_lds(
        (const __attribute__((address_space(1))) void*)g,
        (__attribute__((address_space(3))) void*)l, 16, 0, 0);
}

// XOR-swizzle: 16B chunks within each 64-col group, keyed by row&7 (global-side)
__device__ __forceinline__ int swz_col(int col, int row) {
    return (col & ~63) | ((((col >> 3) & 7) ^ (row & 7)) << 3) | (col & 7);
}

__device__ __forceinline__ bf16x8 cvt8(float4 a, float4 b) {
    bf16x8 w;
    w[0]=(__bf16)a.x; w[1]=(__bf16)a.y; w[2]=(__bf16)a.z; w[3]=(__bf16)a.w;
    w[4]=(__bf16)b.x; w[5]=(__bf16)b.y; w[6]=(__bf16)b.z; w[7]=(__bf16)b.w;
    return w;
}

// ---------------------------------------------------------------------------
// fp32 -> bf16 swizzled convert, W only (R7 lesson: keep this kernel).
// ---------------------------------------------------------------------------
__global__ __launch_bounds__(256) void cvt_W(const float* __restrict__ Wq,
                                             const float* __restrict__ Wk,
                                             const float* __restrict__ Wv,
                                             const float* __restrict__ Wo,
                                             bf16_t* __restrict__ Wc) {
    const int b2 = blockIdx.x;
    const int m = b2 >> 7;                   // which W
    const float* src = m == 0 ? Wq : m == 1 ? Wk : m == 2 ? Wv : Wo;
    const float sc = (m == 0) ? 0.125f * 1.44269504088896f : 1.0f;
    size_t i = ((size_t)(b2 & 127) * 256 + threadIdx.x) * 8;
    int row = (int)(i >> 9), col = (int)(i & 511);
    float4 a0 = *(const float4*)(src + i), a1 = *(const float4*)(src + i + 4);
    bf16x8 o;
    o[0]=(__bf16)(a0.x*sc); o[1]=(__bf16)(a0.y*sc); o[2]=(__bf16)(a0.z*sc); o[3]=(__bf16)(a0.w*sc);
    o[4]=(__bf16)(a1.x*sc); o[5]=(__bf16)(a1.y*sc); o[6]=(__bf16)(a1.z*sc); o[7]=(__bf16)(a1.w*sc);
    *(bf16x8*)(Wc + (size_t)m * 262144 + (size_t)row * 512 + swz_col(col, row)) = o;
}

// ---------------------------------------------------------------------------
// 128x128-tile NT GEMM (R5's proven single-buffered body), LDS by pointer
// (R10 finding: per-instantiation __shared__ arrays are NOT merged).
//   AF32/BF32 = 1: fp32 operand; reg-load 32B/lane, cvt, Latin-square-swizzled
//     ds_write_b128. 0: pre-swizzled bf16; global_load_lds direct.
// ---------------------------------------------------------------------------
template<int MODE, int AF32, int BF32>
__device__ __forceinline__ void gemm128_body(__bf16* __restrict__ Asm,
                                             __bf16* __restrict__ Bsm,
                                             const bf16_t* __restrict__ Ab,
                                             const float* __restrict__ Af,
                                             const bf16_t* __restrict__ Bb,
                                             const float* __restrict__ Bf,
                                             void* __restrict__ outp,
                                             int m0, int n0) {
    const int tid  = threadIdx.x;
    const int wave = tid >> 6;
    const int lane = tid & 63;
    const int quad = lane >> 4;
    const int l16  = lane & 15;
    const int swz  = l16 & 7;
    const int r8 = lane >> 3;
    const int c8 = (lane & 7) * 8;
    const int mrow0 = (wave & 1) * 64;
    const int ncol0 = (wave >> 1) * 64;

    f32x4 acc[4][4];
    for (int i = 0; i < 4; ++i)
        for (int j = 0; j < 4; ++j) acc[i][j] = (f32x4){0.f, 0.f, 0.f, 0.f};

    for (int kt = 0; kt < 512; kt += 64) {
        __syncthreads();
        for (int j = 0; j < 4; ++j) {
            const int rl = wave * 32 + j * 8 + r8;
            if (AF32) {
                const float* s = Af + (size_t)(m0 + rl) * 512 + kt + c8;
                float4 v0 = *(const float4*)s, v1 = *(const float4*)(s + 4);
                *(bf16x8*)&Asm[rl * 64 + (((lane & 7) ^ r8) << 3)] = cvt8(v0, v1);
            } else {
                async16(Ab + (size_t)(m0 + rl) * 512 + kt + c8,
                        &Asm[(wave * 32 + j * 8) * 64]);
            }
            if (BF32) {
                const float* s = Bf + (size_t)(n0 + rl) * 512 + kt + c8;
                float4 v0 = *(const float4*)s, v1 = *(const float4*)(s + 4);
                *(bf16x8*)&Bsm[rl * 64 + (((lane & 7) ^ r8) << 3)] = cvt8(v0, v1);
            } else {
                async16(Bb + (size_t)(n0 + rl) * 512 + kt + c8,
                        &Bsm[(wave * 32 + j * 8) * 64]);
            }
        }
        __syncthreads();

        for (int ks = 0; ks < 2; ++ks) {
            bf16x8 af[4];
            for (int mt = 0; mt < 4; ++mt)
                af[mt] = *(const bf16x8*)&Asm[(mrow0 + mt * 16 + l16) * 64 + ((ks * 4 + quad) ^ swz) * 8];
            for (int nt = 0; nt < 4; ++nt) {
                bf16x8 bf = *(const bf16x8*)&Bsm[(ncol0 + nt * 16 + l16) * 64 + ((ks * 4 + quad) ^ swz) * 8];
                for (int mt = 0; mt < 4; ++mt)
                    acc[mt][nt] = mfma_k32(af[mt], bf, acc[mt][nt]);
            }
        }
    }

    if (MODE == 0) {
        bf16_t* out = (bf16_t*)outp;
        for (int nt = 0; nt < 4; ++nt) {
            int e = n0 + ncol0 + nt * 16 + l16;
            int h = e >> 6, el = e & 63;
            for (int mt = 0; mt < 4; ++mt)
                for (int r = 0; r < 4; ++r) {
                    int row = m0 + mrow0 + mt * 16 + quad * 4 + r;   // b*4096+s
                    int b = row >> 12, s = row & 4095;
                    int elp = (((el >> 3) ^ (row & 7)) << 3) | (el & 7);
                    out[(((size_t)(b * 8 + h)) * 4096 + s) * 64 + elp] = (bf16_t)acc[mt][nt][r];
                }
        }
    } else {
        bf16_t* out = (bf16_t*)outp;
        for (int nt = 0; nt < 4; ++nt) {
            int s_g = n0 + ncol0 + nt * 16 + l16;
            int b = s_g >> 12;
            int sbase = (s_g & 4095) & ~63;
            int f = 16 * ((l16 >> 2) & 3) + 4 * nt + (l16 & 3);
            for (int mt = 0; mt < 4; ++mt)
                for (int r = 0; r < 4; ++r) {
                    int e_g = m0 + mrow0 + mt * 16 + quad * 4 + r;
                    int h = e_g >> 6, el = e_g & 63;
                    int col = sbase | ((((f >> 3) ^ (e_g & 7)) & 7) << 3) | (f & 7);
                    out[(((size_t)(b * 8 + h)) * 64 + el) * 4096 + col] = (bf16_t)acc[mt][nt][r];
                }
        }
    }
}

// grid (256,1,3); XCD-sibling swizzle; single kernel-scope 32KB LDS.
__global__ __launch_bounds__(256) void proj_fused(const float* __restrict__ q,
                                                  const float* __restrict__ k,
                                                  const float* __restrict__ v,
                                                  const bf16_t* __restrict__ Wc,
                                                  bf16_t* __restrict__ qh,
                                                  bf16_t* __restrict__ kh,
                                                  bf16_t* __restrict__ vh) {
    __shared__ __bf16 Asm[128 * 64];
    __shared__ __bf16 Bsm[128 * 64];
    const int f = blockIdx.x;
    const int y = (f >> 3) & 3;
    const int x = (f & 7) | ((f >> 5) << 3);
    const int z = blockIdx.z;
    const bf16_t* W = Wc + (size_t)z * 262144;
    if (z == 0)
        gemm128_body<0, 1, 0>(Asm, Bsm, nullptr, q, W, nullptr, qh, x * 128, y * 128);
    else if (z == 1)
        gemm128_body<0, 1, 0>(Asm, Bsm, nullptr, k, W, nullptr, kh, x * 128, y * 128);
    else
        gemm128_body<1, 0, 1>(Asm, Bsm, W, nullptr, nullptr, v, vh, y * 128, x * 128);
}

// ---------------------------------------------------------------------------
// Final GEMM, RETILED 128x128 -> 64x64 (R12): grid 256 -> 1024 blocks
// (1 -> 4 blocks/CU, 4 -> 16 waves/CU). R10 precedent: this kernel's old
// 1-block/CU geometry is exactly the config that made proj take 92us.
// Staging pattern, swizzles, combine math, MFMA mapping unchanged — only
// the tile shrinks: waves 2x2 over 32x32 sub-tiles, acc[2][2]; A/B stage
// 64 rows each (2 j-iters). LDS 16KB. XCD swizzle: same-m0 blocks (8 y's)
// ids 8 apart -> same XCD -> shared Op stripe L2-served.
// ---------------------------------------------------------------------------
__global__ __launch_bounds__(256) void gemm_final(const bf16_t* __restrict__ Op,
                                                  const float* __restrict__ Lp,
                                                  const bf16_t* __restrict__ B,
                                                  float* __restrict__ out) {
    __shared__ __bf16 Asm[64 * 64];
    __shared__ __bf16 Bsm[64 * 64];
    const int fb = blockIdx.x;
    const int yb = (fb >> 3) & 7;
    const int xb = (fb & 7) | ((fb >> 6) << 3);
    const int m0 = xb * 64;
    const int n0 = yb * 64;
    const int tid  = threadIdx.x;
    const int wave = tid >> 6;
    const int lane = tid & 63;
    const int quad = lane >> 4;
    const int l16  = lane & 15;
    const int swz  = l16 & 7;
    const int r8 = lane >> 3;
    const int c8 = (lane & 7) * 8;
    const int mrow0 = (wave & 1) * 32;
    const int ncol0 = (wave >> 1) * 32;

    f32x4 acc[2][2];
    for (int i = 0; i < 2; ++i)
        for (int j = 0; j < 2; ++j) acc[i][j] = (f32x4){0.f, 0.f, 0.f, 0.f};

    for (int kt = 0; kt < 512; kt += 64) {
        const int h = kt >> 6;
        __syncthreads();
        for (int j = 0; j < 2; ++j)
            async16(B + (size_t)(n0 + wave * 16 + j * 8 + r8) * 512 + kt + c8,
                    &Bsm[(wave * 16 + j * 8) * 64]);
        for (int j = 0; j < 2; ++j) {
            const int rl  = wave * 16 + j * 8 + r8;
            const int row = m0 + rl;                 // b*4096 + s
            const int b   = row >> 12, sp = row & 4095;
            const size_t lidx = (size_t)(b * 8 + h) * 4096 + sp;
            bf16x8 a0 = *(const bf16x8*)(Op + lidx * 64 + c8);
            bf16x8 a1 = *(const bf16x8*)(Op + 4194304 + lidx * 64 + c8);
            float inv = 1.0f / (Lp[lidx] + Lp[65536 + lidx]);
            bf16x8 w;
            for (int i = 0; i < 8; ++i)
                w[i] = (bf16_t)(((float)a0[i] + (float)a1[i]) * inv);
            *(bf16x8*)&Asm[rl * 64 + (((lane & 7) ^ r8) << 3)] = w;
        }
        __syncthreads();

        for (int ks = 0; ks < 2; ++ks) {
            bf16x8 af[2];
            for (int mt = 0; mt < 2; ++mt)
                af[mt] = *(const bf16x8*)&Asm[(mrow0 + mt * 16 + l16) * 64 + ((ks * 4 + quad) ^ swz) * 8];
            for (int nt = 0; nt < 2; ++nt) {
                bf16x8 bf = *(const bf16x8*)&Bsm[(ncol0 + nt * 16 + l16) * 64 + ((ks * 4 + quad) ^ swz) * 8];
                for (int mt = 0; mt < 2; ++mt)
                    acc[mt][nt] = mfma_k32(af[mt], bf, acc[mt][nt]);
            }
        }
    }

    for (int nt = 0; nt < 2; ++nt) {
        int n = n0 + ncol0 + nt * 16 + l16;
        for (int mt = 0; mt < 2; ++mt)
            for (int r = 0; r < 4; ++r) {
                int row = m0 + mrow0 + mt * 16 + quad * 4 + r;
                out[(size_t)row * 512 + n] = acc[mt][nt][r];
            }
    }
}

// ---------------------------------------------------------------------------
// Causal flash attention v7 (verbatim R2/R5 winner, 62.2-62.6us): FROZEN.
// Four restructure attempts failed; root cause: 64 VGPR + 64 AGPR = the
// full 128-reg budget at (256,4) — any added live state spills.
// ---------------------------------------------------------------------------
__global__ __launch_bounds__(256, 4) void attn_kernel(const bf16_t* __restrict__ qh,
                                                      const bf16_t* __restrict__ kh,
                                                      const bf16_t* __restrict__ vh,
                                                      bf16_t* __restrict__ Opart,
                                                      float* __restrict__ Lpart) {
    __shared__ __bf16 SM[16384];            // 32 KB: K panels [2][64][64] + V panels
    __bf16* KSM = &SM[0];
    __bf16* VSM = &SM[8192];
    float* Osc = (float*)SM;                // 16.6 KB leg-end scratch [q][65]
    float* Lsc = (float*)&SM[8320];         // 256 B lsum scratch [q] (byte 16640)

    const int id   = blockIdx.x;
    const int bh   = ((id & 7) << 1) | ((id >> 3) & 1);   // XCD-grouped
    const int pair = (id >> 4) & 31;
    const int z    = (id >> 9) & 1;

    const int tid  = threadIdx.x;
    const int wave = tid >> 6;
    const int g2   = wave >> 1;             // K-panel parity within step
    const int wl   = wave & 1;              // query half
    const int lane = tid & 63;
    const int quad = lane >> 4;
    const int l16  = lane & 15;
    const int swz  = l16 & 7;
    const size_t base = (size_t)bh * 4096 * 64;
    const int r8 = lane >> 3;
    const int c8 = (lane & 7) * 8;

    bf16_t* Op = Opart + (size_t)z * 4194304;
    float*  Lp = Lpart + z * 65536;

    for (int leg = 0; leg < 2; ++leg) {
        const int qt = leg ? (63 - pair) : pair;
        const int q0 = qt * 64;

        bf16x8 qf[2][2];
        for (int g = 0; g < 2; ++g) {
            const bf16_t* qp = qh + base + (size_t)(q0 + wl * 32 + g * 16 + l16) * 64;
            qf[g][0] = *(const bf16x8*)(qp + ((quad ^ swz) * 8));
            qf[g][1] = *(const bf16x8*)(qp + (((4 + quad) ^ swz) * 8));
        }

        f32x4 o[2][4];
        for (int g = 0; g < 2; ++g)
            for (int i = 0; i < 4; ++i) o[g][i] = (f32x4){0.f, 0.f, 0.f, 0.f};
        float lsum[2] = {0.f, 0.f};

        const int S  = (qt + 2) >> 1;       // total 128-key steps of this leg
        const int Sh = (S + 1) >> 1;        // z=0 takes [0,Sh), z=1 takes [Sh,S)
        const int it0 = z ? Sh : 0;
        const int it1 = z ? S : Sh;

        for (int it = it0; it < it1; ++it) {
            const int j0 = it * 128;
            __syncthreads();
            for (int p = 0; p < 2; ++p)
                for (int j = 0; j < 2; ++j) {
                    int row = wave * 16 + j * 8 + r8;
                    async16(kh + base + (size_t)(j0 + p * 64 + row) * 64 + c8,
                            KSM + (p * 64 + wave * 16 + j * 8) * 64);
                    async16(vh + (size_t)(bh * 64 + row) * 4096 + j0 + p * 64 + c8,
                            VSM + (p * 64 + wave * 16 + j * 8) * 64);
                }
            __syncthreads();

            const int pp = g2;
            const int koff = j0 + pp * 64 - q0;
            if (koff > wl * 32 + 31) continue;     // fully masked for this wave

            // S^T = K·Q^T (C: col=query=l16, row=key=nt*16+quad*4+r)
            f32x4 st[2][4];
            for (int nt = 0; nt < 4; ++nt) {
                const __bf16* kr = KSM + (pp * 64 + nt * 16 + l16) * 64;
                bf16x8 kf0 = *(const bf16x8*)(kr + ((quad ^ swz) * 8));
                bf16x8 kf1 = *(const bf16x8*)(kr + (((4 + quad) ^ swz) * 8));
                for (int g = 0; g < 2; ++g) {
                    f32x4 zz = (f32x4){0.f, 0.f, 0.f, 0.f};
                    zz = mfma_k32(kf0, qf[g][0], zz);
                    zz = mfma_k32(kf1, qf[g][1], zz);
                    st[g][nt] = zz;
                }
            }

            // fixed-base softmax: p = exp2(st)
            bf16x4 pf[2][4];
            for (int g = 0; g < 2; ++g) {
                const int qb = wl * 32 + g * 16;
                if (koff + 63 <= qb) {
                    for (int nt = 0; nt < 4; ++nt)
                        for (int r = 0; r < 4; ++r) {
                            float p = fast_exp2(st[g][nt][r]);
                            lsum[g] += p;
                            pf[g][nt][r] = (bf16_t)p;
                        }
                } else {
                    const int qrow = qb + l16;
                    for (int nt = 0; nt < 4; ++nt)
                        for (int r = 0; r < 4; ++r) {
                            int key = nt * 16 + quad * 4 + r;
                            float p = (key + koff <= qrow) ? fast_exp2(st[g][nt][r]) : 0.f;
                            lsum[g] += p;
                            pf[g][nt][r] = (bf16_t)p;
                        }
                }
            }

            // O += P·V (P register-resident)
            for (int dt = 0; dt < 4; ++dt)
                for (int kt2 = 0; kt2 < 2; ++kt2) {
                    bf16x8 vf = *(const bf16x8*)&VSM[(pp * 64 + dt * 16 + l16) * 64 + (((2 * quad + kt2) ^ swz) * 8)];
                    bf16x4 vlo = {vf[0], vf[1], vf[2], vf[3]};
                    bf16x4 vhi = {vf[4], vf[5], vf[6], vf[7]};
                    for (int g = 0; g < 2; ++g) {
                        o[g][dt] = mfma_k16(pf[g][2 * kt2], vlo, o[g][dt]);
                        o[g][dt] = mfma_k16(pf[g][2 * kt2 + 1], vhi, o[g][dt]);
                    }
                }
        }

        // ---- combine K-parity partials within block, write leg partials ----
        __syncthreads();                    // all K/V LDS reads done
        if (g2 == 1) {
            for (int g = 0; g < 2; ++g) {
                float ls = lsum[g];
                ls += __shfl_xor(ls, 16);
                ls += __shfl_xor(ls, 32);
                const int qb = wl * 32 + g * 16;
                Lsc[qb + l16] = ls;
                for (int dt = 0; dt < 4; ++dt)
                    for (int r = 0; r < 4; ++r)
                        Osc[(qb + quad * 4 + r) * 65 + dt * 16 + l16] = o[g][dt][r];
            }
        }
        __syncthreads();
        if (g2 == 0) {
            for (int g = 0; g < 2; ++g) {
                float ls = lsum[g];
                ls += __shfl_xor(ls, 16);
                ls += __shfl_xor(ls, 32);
                const int qb = wl * 32 + g * 16;
                ls += Lsc[qb + l16];
                Lsc[qb + l16] = ls;         // total lsum for this z
                for (int dt = 0; dt < 4; ++dt)
                    for (int r = 0; r < 4; ++r) {
                        int idx = (qb + quad * 4 + r) * 65 + dt * 16 + l16;
                        Osc[idx] = o[g][dt][r] + Osc[idx];
                    }
            }
        }
        __syncthreads();
        // repack: contiguous bf16 partial rows [q][e] + fp32 lsum
        {
            const int q  = tid >> 2;
            const int e0 = (tid & 3) * 16;
            bf16x8 w0, w1;
            for (int i = 0; i < 8; ++i) {
                w0[i] = (bf16_t)Osc[q * 65 + e0 + i];
                w1[i] = (bf16_t)Osc[q * 65 + e0 + 8 + i];
            }
            size_t slot = ((size_t)(bh * 64 + qt)) * 4096 + q * 64 + e0;
            *(bf16x8*)&Op[slot]     = w0;
            *(bf16x8*)&Op[slot + 8] = w1;
            if (tid < 64) Lp[(bh * 64 + qt) * 64 + tid] = Lsc[tid];
        }
        // next leg's first __syncthreads() protects Osc/Lsc reuse
    }
}

// ---------------------------------------------------------------------------
extern "C" void kernel_launch(void* const* d_in, const int* in_sizes, int n_in,
                              void* d_out, int out_size, void* d_ws, size_t ws_size,
                              hipStream_t stream) {
    const float* q  = (const float*)d_in[0];
    const float* k  = (const float*)d_in[1];
    const float* v  = (const float*)d_in[2];
    const float* Wq = (const float*)d_in[3];
    const float* Wk = (const float*)d_in[4];
    const float* Wv = (const float*)d_in[5];
    const float* Wo = (const float*)d_in[6];
    float* out = (float*)d_out;

    bf16_t* ws = (bf16_t*)d_ws;
    const size_t R = (size_t)8192 * 512;   // 4.19M elems = 8.39 MB per region
    bf16_t* opart = ws + R;          // R1+R2: Opart z0/z1
    bf16_t* vh = ws + 3 * R;         // R3: V^T heads
    bf16_t* Wc = ws + 4 * R;         // +2 MB bf16 weights (Wq pre-scaled)
    float*  Lp = (float*)(ws + 4 * R + 1048576);  // +0.5 MB lsum partials
    bf16_t* qh = (bf16_t*)d_out;     // qh/kh in d_out, dead before final GEMM
    bf16_t* kh = (bf16_t*)d_out + R;

    cvt_W<<<dim3(512), dim3(256), 0, stream>>>(Wq, Wk, Wv, Wo, Wc);
    proj_fused<<<dim3(256, 1, 3), dim3(256), 0, stream>>>(q, k, v, Wc, qh, kh, vh);
    attn_kernel<<<dim3(1024), dim3(256), 0, stream>>>(qh, kh, vh, opart, Lp);
    gemm_final<<<dim3(1024), dim3(256), 0, stream>>>(opart, Lp, Wc + 3 * 262144, out);
}

// Round 13
// 230.558 us; speedup vs baseline: 1.4718x; 1.0128x over previous
//
#include <hip/hip_runtime.h>
#include <hip/hip_bf16.h>
#include <math.h>

typedef __bf16 bf16_t;
typedef __bf16 bf16x8 __attribute__((ext_vector_type(8)));
typedef __bf16 bf16x4 __attribute__((ext_vector_type(4)));
typedef short short4v __attribute__((ext_vector_type(4)));
typedef float f32x4 __attribute__((ext_vector_type(4)));

__device__ __forceinline__ f32x4 mfma_k32(bf16x8 a, bf16x8 b, f32x4 c) {
    return __builtin_amdgcn_mfma_f32_16x16x32_bf16(a, b, c, 0, 0, 0);
}

__device__ __forceinline__ f32x4 mfma_k16(bf16x4 a, bf16x4 b, f32x4 c) {
#if __has_builtin(__builtin_amdgcn_mfma_f32_16x16x16_bf16)
    return __builtin_amdgcn_mfma_f32_16x16x16_bf16(a, b, c, 0, 0, 0);
#elif __has_builtin(__builtin_amdgcn_mfma_f32_16x16x16bf16_1k)
    short4v as, bs;
    __builtin_memcpy(&as, &a, 8);
    __builtin_memcpy(&bs, &b, 8);
    return __builtin_amdgcn_mfma_f32_16x16x16bf16_1k(as, bs, c, 0, 0, 0);
#else
    f32x4 d = c;
    asm volatile("v_mfma_f32_16x16x16_bf16 %0, %1, %2, %0" : "+v"(d) : "v"(a), "v"(b));
    return d;
#endif
}

// raw v_exp_f32 (exp2): avoid OCML guard code around exp2f
__device__ __forceinline__ float fast_exp2(float x) {
#if __has_builtin(__builtin_amdgcn_exp2f)
    return __builtin_amdgcn_exp2f(x);
#else
    float r;
    asm("v_exp_f32 %0, %1" : "=v"(r) : "v"(x));
    return r;
#endif
}

// async global->LDS, 16B/lane; LDS dest = wave-uniform base + lane*16
__device__ __forceinline__ void async16(const bf16_t* g, __bf16* l) {
    __builtin_amdgcn_global_load_lds(
        (const __attribute__((address_space(1))) void*)g,
        (__attribute__((address_space(3))) void*)l, 16, 0, 0);
}

// XOR-swizzle: 16B chunks within each 64-col group, keyed by row&7 (global-side)
__device__ __forceinline__ int swz_col(int col, int row) {
    return (col & ~63) | ((((col >> 3) & 7) ^ (row & 7)) << 3) | (col & 7);
}

__device__ __forceinline__ bf16x8 cvt8(float4 a, float4 b) {
    bf16x8 w;
    w[0]=(__bf16)a.x; w[1]=(__bf16)a.y; w[2]=(__bf16)a.z; w[3]=(__bf16)a.w;
    w[4]=(__bf16)b.x; w[5]=(__bf16)b.y; w[6]=(__bf16)b.z; w[7]=(__bf16)b.w;
    return w;
}

// ---------------------------------------------------------------------------
// fp32 -> bf16 swizzled convert, W only (R7 lesson: keep this kernel).
// ---------------------------------------------------------------------------
__global__ __launch_bounds__(256) void cvt_W(const float* __restrict__ Wq,
                                             const float* __restrict__ Wk,
                                             const float* __restrict__ Wv,
                                             const float* __restrict__ Wo,
                                             bf16_t* __restrict__ Wc) {
    const int b2 = blockIdx.x;
    const int m = b2 >> 7;                   // which W
    const float* src = m == 0 ? Wq : m == 1 ? Wk : m == 2 ? Wv : Wo;
    const float sc = (m == 0) ? 0.125f * 1.44269504088896f : 1.0f;
    size_t i = ((size_t)(b2 & 127) * 256 + threadIdx.x) * 8;
    int row = (int)(i >> 9), col = (int)(i & 511);
    float4 a0 = *(const float4*)(src + i), a1 = *(const float4*)(src + i + 4);
    bf16x8 o;
    o[0]=(__bf16)(a0.x*sc); o[1]=(__bf16)(a0.y*sc); o[2]=(__bf16)(a0.z*sc); o[3]=(__bf16)(a0.w*sc);
    o[4]=(__bf16)(a1.x*sc); o[5]=(__bf16)(a1.y*sc); o[6]=(__bf16)(a1.z*sc); o[7]=(__bf16)(a1.w*sc);
    *(bf16x8*)(Wc + (size_t)m * 262144 + (size_t)row * 512 + swz_col(col, row)) = o;
}

// ---------------------------------------------------------------------------
// Per-operand 64-wide sub-tile staging (proven R4/R5 patterns, unchanged):
//   F32=1: fp32 reg-load 32B/lane, cvt, Latin-square-swizzled ds_write_b128.
//   F32=0: pre-swizzled bf16 via global_load_lds direct.
// ---------------------------------------------------------------------------
template<int F32>
__device__ __forceinline__ void stage64(__bf16* __restrict__ Sm,
                                        const bf16_t* __restrict__ Gb,
                                        const float* __restrict__ Gf,
                                        int row0, int kt,
                                        int wave, int r8, int c8, int lane) {
#pragma unroll
    for (int j = 0; j < 4; ++j) {
        const int rl = wave * 32 + j * 8 + r8;
        if (F32) {
            const float* s = Gf + (size_t)(row0 + rl) * 512 + kt + c8;
            float4 v0 = *(const float4*)s, v1 = *(const float4*)(s + 4);
            *(bf16x8*)&Sm[rl * 64 + (((lane & 7) ^ r8) << 3)] = cvt8(v0, v1);
        } else {
            async16(Gb + (size_t)(row0 + rl) * 512 + kt + c8,
                    &Sm[(wave * 32 + j * 8) * 64]);
        }
    }
}

// ---------------------------------------------------------------------------
// 128x128-tile NT GEMM, BK=128 as TWO 64-wide sub-tiles (R13): per outer
// step stage {Asm0<-k..k+64, Asm1<-k+64..k+128} + same for B, ONE barrier
// pair, compute both halves (32 MFMA/phase). Drain/barrier events: 16 -> 8
// (proj is 2-phase-stall-bound per m233; R11 proved 2 blocks/CU suffices,
// so the 64KB LDS cost is free). Sub-tile layout/swizzle/reader arithmetic
// byte-identical to the proven [128][64] form. LDS by pointer (R10 lesson:
// per-instantiation __shared__ is NOT merged).
// ---------------------------------------------------------------------------
template<int MODE, int AF32, int BF32>
__device__ __forceinline__ void gemm128_body(__bf16* __restrict__ Asm0,
                                             __bf16* __restrict__ Asm1,
                                             __bf16* __restrict__ Bsm0,
                                             __bf16* __restrict__ Bsm1,
                                             const bf16_t* __restrict__ Ab,
                                             const float* __restrict__ Af,
                                             const bf16_t* __restrict__ Bb,
                                             const float* __restrict__ Bf,
                                             void* __restrict__ outp,
                                             int m0, int n0) {
    const int tid  = threadIdx.x;
    const int wave = tid >> 6;
    const int lane = tid & 63;
    const int quad = lane >> 4;
    const int l16  = lane & 15;
    const int swz  = l16 & 7;
    const int r8 = lane >> 3;
    const int c8 = (lane & 7) * 8;
    const int mrow0 = (wave & 1) * 64;
    const int ncol0 = (wave >> 1) * 64;

    f32x4 acc[4][4];
    for (int i = 0; i < 4; ++i)
        for (int j = 0; j < 4; ++j) acc[i][j] = (f32x4){0.f, 0.f, 0.f, 0.f};

    for (int kt = 0; kt < 512; kt += 128) {
        __syncthreads();
        stage64<AF32>(Asm0, Ab, Af, m0, kt,      wave, r8, c8, lane);
        stage64<AF32>(Asm1, Ab, Af, m0, kt + 64, wave, r8, c8, lane);
        stage64<BF32>(Bsm0, Bb, Bf, n0, kt,      wave, r8, c8, lane);
        stage64<BF32>(Bsm1, Bb, Bf, n0, kt + 64, wave, r8, c8, lane);
        __syncthreads();

#pragma unroll
        for (int half = 0; half < 2; ++half) {
            const __bf16* As = half ? Asm1 : Asm0;
            const __bf16* Bs = half ? Bsm1 : Bsm0;
            for (int ks = 0; ks < 2; ++ks) {
                bf16x8 af[4];
                for (int mt = 0; mt < 4; ++mt)
                    af[mt] = *(const bf16x8*)&As[(mrow0 + mt * 16 + l16) * 64 + ((ks * 4 + quad) ^ swz) * 8];
                for (int nt = 0; nt < 4; ++nt) {
                    bf16x8 bf = *(const bf16x8*)&Bs[(ncol0 + nt * 16 + l16) * 64 + ((ks * 4 + quad) ^ swz) * 8];
                    for (int mt = 0; mt < 4; ++mt)
                        acc[mt][nt] = mfma_k32(af[mt], bf, acc[mt][nt]);
                }
            }
        }
    }

    if (MODE == 0) {
        bf16_t* out = (bf16_t*)outp;
        for (int nt = 0; nt < 4; ++nt) {
            int e = n0 + ncol0 + nt * 16 + l16;
            int h = e >> 6, el = e & 63;
            for (int mt = 0; mt < 4; ++mt)
                for (int r = 0; r < 4; ++r) {
                    int row = m0 + mrow0 + mt * 16 + quad * 4 + r;   // b*4096+s
                    int b = row >> 12, s = row & 4095;
                    int elp = (((el >> 3) ^ (row & 7)) << 3) | (el & 7);
                    out[(((size_t)(b * 8 + h)) * 4096 + s) * 64 + elp] = (bf16_t)acc[mt][nt][r];
                }
        }
    } else {
        bf16_t* out = (bf16_t*)outp;
        for (int nt = 0; nt < 4; ++nt) {
            int s_g = n0 + ncol0 + nt * 16 + l16;
            int b = s_g >> 12;
            int sbase = (s_g & 4095) & ~63;
            int f = 16 * ((l16 >> 2) & 3) + 4 * nt + (l16 & 3);
            for (int mt = 0; mt < 4; ++mt)
                for (int r = 0; r < 4; ++r) {
                    int e_g = m0 + mrow0 + mt * 16 + quad * 4 + r;
                    int h = e_g >> 6, el = e_g & 63;
                    int col = sbase | ((((f >> 3) ^ (e_g & 7)) & 7) << 3) | (f & 7);
                    out[(((size_t)(b * 8 + h)) * 64 + el) * 4096 + col] = (bf16_t)acc[mt][nt][r];
                }
        }
    }
}

// grid (256,1,3); XCD-sibling swizzle; single kernel-scope 64KB LDS shared
// by all instantiations (2 blocks/CU — R11 proved sufficient for proj).
__global__ __launch_bounds__(256) void proj_fused(const float* __restrict__ q,
                                                  const float* __restrict__ k,
                                                  const float* __restrict__ v,
                                                  const bf16_t* __restrict__ Wc,
                                                  bf16_t* __restrict__ qh,
                                                  bf16_t* __restrict__ kh,
                                                  bf16_t* __restrict__ vh) {
    __shared__ __bf16 Asm[2][128 * 64];
    __shared__ __bf16 Bsm[2][128 * 64];
    const int f = blockIdx.x;
    const int y = (f >> 3) & 3;
    const int x = (f & 7) | ((f >> 5) << 3);
    const int z = blockIdx.z;
    const bf16_t* W = Wc + (size_t)z * 262144;
    if (z == 0)
        gemm128_body<0, 1, 0>(Asm[0], Asm[1], Bsm[0], Bsm[1], nullptr, q, W, nullptr, qh, x * 128, y * 128);
    else if (z == 1)
        gemm128_body<0, 1, 0>(Asm[0], Asm[1], Bsm[0], Bsm[1], nullptr, k, W, nullptr, kh, x * 128, y * 128);
    else
        gemm128_body<1, 0, 1>(Asm[0], Asm[1], Bsm[0], Bsm[1], W, nullptr, nullptr, v, vh, y * 128, x * 128);
}

// ---------------------------------------------------------------------------
// Final GEMM, 64x64 tiles (R12 winner, byte-identical): grid 1024 = 4
// blocks/CU; fused z-combine + softmax normalization in A-staging; B =
// pre-converted bf16 Wo via async16; XCD swizzle.
// ---------------------------------------------------------------------------
__global__ __launch_bounds__(256) void gemm_final(const bf16_t* __restrict__ Op,
                                                  const float* __restrict__ Lp,
                                                  const bf16_t* __restrict__ B,
                                                  float* __restrict__ out) {
    __shared__ __bf16 Asm[64 * 64];
    __shared__ __bf16 Bsm[64 * 64];
    const int fb = blockIdx.x;
    const int yb = (fb >> 3) & 7;
    const int xb = (fb & 7) | ((fb >> 6) << 3);
    const int m0 = xb * 64;
    const int n0 = yb * 64;
    const int tid  = threadIdx.x;
    const int wave = tid >> 6;
    const int lane = tid & 63;
    const int quad = lane >> 4;
    const int l16  = lane & 15;
    const int swz  = l16 & 7;
    const int r8 = lane >> 3;
    const int c8 = (lane & 7) * 8;
    const int mrow0 = (wave & 1) * 32;
    const int ncol0 = (wave >> 1) * 32;

    f32x4 acc[2][2];
    for (int i = 0; i < 2; ++i)
        for (int j = 0; j < 2; ++j) acc[i][j] = (f32x4){0.f, 0.f, 0.f, 0.f};

    for (int kt = 0; kt < 512; kt += 64) {
        const int h = kt >> 6;
        __syncthreads();
        for (int j = 0; j < 2; ++j)
            async16(B + (size_t)(n0 + wave * 16 + j * 8 + r8) * 512 + kt + c8,
                    &Bsm[(wave * 16 + j * 8) * 64]);
        for (int j = 0; j < 2; ++j) {
            const int rl  = wave * 16 + j * 8 + r8;
            const int row = m0 + rl;                 // b*4096 + s
            const int b   = row >> 12, sp = row & 4095;
            const size_t lidx = (size_t)(b * 8 + h) * 4096 + sp;
            bf16x8 a0 = *(const bf16x8*)(Op + lidx * 64 + c8);
            bf16x8 a1 = *(const bf16x8*)(Op + 4194304 + lidx * 64 + c8);
            float inv = 1.0f / (Lp[lidx] + Lp[65536 + lidx]);
            bf16x8 w;
            for (int i = 0; i < 8; ++i)
                w[i] = (bf16_t)(((float)a0[i] + (float)a1[i]) * inv);
            *(bf16x8*)&Asm[rl * 64 + (((lane & 7) ^ r8) << 3)] = w;
        }
        __syncthreads();

        for (int ks = 0; ks < 2; ++ks) {
            bf16x8 af[2];
            for (int mt = 0; mt < 2; ++mt)
                af[mt] = *(const bf16x8*)&Asm[(mrow0 + mt * 16 + l16) * 64 + ((ks * 4 + quad) ^ swz) * 8];
            for (int nt = 0; nt < 2; ++nt) {
                bf16x8 bf = *(const bf16x8*)&Bsm[(ncol0 + nt * 16 + l16) * 64 + ((ks * 4 + quad) ^ swz) * 8];
                for (int mt = 0; mt < 2; ++mt)
                    acc[mt][nt] = mfma_k32(af[mt], bf, acc[mt][nt]);
            }
        }
    }

    for (int nt = 0; nt < 2; ++nt) {
        int n = n0 + ncol0 + nt * 16 + l16;
        for (int mt = 0; mt < 2; ++mt)
            for (int r = 0; r < 4; ++r) {
                int row = m0 + mrow0 + mt * 16 + quad * 4 + r;
                out[(size_t)row * 512 + n] = acc[mt][nt][r];
            }
    }
}

// ---------------------------------------------------------------------------
// Causal flash attention v7 (verbatim R2/R5 winner, 62.2-62.6us): FROZEN.
// Four restructure attempts failed; root cause: 64 VGPR + 64 AGPR = the
// full 128-reg budget at (256,4) — any added live state spills.
// ---------------------------------------------------------------------------
__global__ __launch_bounds__(256, 4) void attn_kernel(const bf16_t* __restrict__ qh,
                                                      const bf16_t* __restrict__ kh,
                                                      const bf16_t* __restrict__ vh,
                                                      bf16_t* __restrict__ Opart,
                                                      float* __restrict__ Lpart) {
    __shared__ __bf16 SM[16384];            // 32 KB: K panels [2][64][64] + V panels
    __bf16* KSM = &SM[0];
    __bf16* VSM = &SM[8192];
    float* Osc = (float*)SM;                // 16.6 KB leg-end scratch [q][65]
    float* Lsc = (float*)&SM[8320];         // 256 B lsum scratch [q] (byte 16640)

    const int id   = blockIdx.x;
    const int bh   = ((id & 7) << 1) | ((id >> 3) & 1);   // XCD-grouped
    const int pair = (id >> 4) & 31;
    const int z    = (id >> 9) & 1;

    const int tid  = threadIdx.x;
    const int wave = tid >> 6;
    const int g2   = wave >> 1;             // K-panel parity within step
    const int wl   = wave & 1;              // query half
    const int lane = tid & 63;
    const int quad = lane >> 4;
    const int l16  = lane & 15;
    const int swz  = l16 & 7;
    const size_t base = (size_t)bh * 4096 * 64;
    const int r8 = lane >> 3;
    const int c8 = (lane & 7) * 8;

    bf16_t* Op = Opart + (size_t)z * 4194304;
    float*  Lp = Lpart + z * 65536;

    for (int leg = 0; leg < 2; ++leg) {
        const int qt = leg ? (63 - pair) : pair;
        const int q0 = qt * 64;

        bf16x8 qf[2][2];
        for (int g = 0; g < 2; ++g) {
            const bf16_t* qp = qh + base + (size_t)(q0 + wl * 32 + g * 16 + l16) * 64;
            qf[g][0] = *(const bf16x8*)(qp + ((quad ^ swz) * 8));
            qf[g][1] = *(const bf16x8*)(qp + (((4 + quad) ^ swz) * 8));
        }

        f32x4 o[2][4];
        for (int g = 0; g < 2; ++g)
            for (int i = 0; i < 4; ++i) o[g][i] = (f32x4){0.f, 0.f, 0.f, 0.f};
        float lsum[2] = {0.f, 0.f};

        const int S  = (qt + 2) >> 1;       // total 128-key steps of this leg
        const int Sh = (S + 1) >> 1;        // z=0 takes [0,Sh), z=1 takes [Sh,S)
        const int it0 = z ? Sh : 0;
        const int it1 = z ? S : Sh;

        for (int it = it0; it < it1; ++it) {
            const int j0 = it * 128;
            __syncthreads();
            for (int p = 0; p < 2; ++p)
                for (int j = 0; j < 2; ++j) {
                    int row = wave * 16 + j * 8 + r8;
                    async16(kh + base + (size_t)(j0 + p * 64 + row) * 64 + c8,
                            KSM + (p * 64 + wave * 16 + j * 8) * 64);
                    async16(vh + (size_t)(bh * 64 + row) * 4096 + j0 + p * 64 + c8,
                            VSM + (p * 64 + wave * 16 + j * 8) * 64);
                }
            __syncthreads();

            const int pp = g2;
            const int koff = j0 + pp * 64 - q0;
            if (koff > wl * 32 + 31) continue;     // fully masked for this wave

            // S^T = K·Q^T (C: col=query=l16, row=key=nt*16+quad*4+r)
            f32x4 st[2][4];
            for (int nt = 0; nt < 4; ++nt) {
                const __bf16* kr = KSM + (pp * 64 + nt * 16 + l16) * 64;
                bf16x8 kf0 = *(const bf16x8*)(kr + ((quad ^ swz) * 8));
                bf16x8 kf1 = *(const bf16x8*)(kr + (((4 + quad) ^ swz) * 8));
                for (int g = 0; g < 2; ++g) {
                    f32x4 zz = (f32x4){0.f, 0.f, 0.f, 0.f};
                    zz = mfma_k32(kf0, qf[g][0], zz);
                    zz = mfma_k32(kf1, qf[g][1], zz);
                    st[g][nt] = zz;
                }
            }

            // fixed-base softmax: p = exp2(st)
            bf16x4 pf[2][4];
            for (int g = 0; g < 2; ++g) {
                const int qb = wl * 32 + g * 16;
                if (koff + 63 <= qb) {
                    for (int nt = 0; nt < 4; ++nt)
                        for (int r = 0; r < 4; ++r) {
                            float p = fast_exp2(st[g][nt][r]);
                            lsum[g] += p;
                            pf[g][nt][r] = (bf16_t)p;
                        }
                } else {
                    const int qrow = qb + l16;
                    for (int nt = 0; nt < 4; ++nt)
                        for (int r = 0; r < 4; ++r) {
                            int key = nt * 16 + quad * 4 + r;
                            float p = (key + koff <= qrow) ? fast_exp2(st[g][nt][r]) : 0.f;
                            lsum[g] += p;
                            pf[g][nt][r] = (bf16_t)p;
                        }
                }
            }

            // O += P·V (P register-resident)
            for (int dt = 0; dt < 4; ++dt)
                for (int kt2 = 0; kt2 < 2; ++kt2) {
                    bf16x8 vf = *(const bf16x8*)&VSM[(pp * 64 + dt * 16 + l16) * 64 + (((2 * quad + kt2) ^ swz) * 8)];
                    bf16x4 vlo = {vf[0], vf[1], vf[2], vf[3]};
                    bf16x4 vhi = {vf[4], vf[5], vf[6], vf[7]};
                    for (int g = 0; g < 2; ++g) {
                        o[g][dt] = mfma_k16(pf[g][2 * kt2], vlo, o[g][dt]);
                        o[g][dt] = mfma_k16(pf[g][2 * kt2 + 1], vhi, o[g][dt]);
                    }
                }
        }

        // ---- combine K-parity partials within block, write leg partials ----
        __syncthreads();                    // all K/V LDS reads done
        if (g2 == 1) {
            for (int g = 0; g < 2; ++g) {
                float ls = lsum[g];
                ls += __shfl_xor(ls, 16);
                ls += __shfl_xor(ls, 32);
                const int qb = wl * 32 + g * 16;
                Lsc[qb + l16] = ls;
                for (int dt = 0; dt < 4; ++dt)
                    for (int r = 0; r < 4; ++r)
                        Osc[(qb + quad * 4 + r) * 65 + dt * 16 + l16] = o[g][dt][r];
            }
        }
        __syncthreads();
        if (g2 == 0) {
            for (int g = 0; g < 2; ++g) {
                float ls = lsum[g];
                ls += __shfl_xor(ls, 16);
                ls += __shfl_xor(ls, 32);
                const int qb = wl * 32 + g * 16;
                ls += Lsc[qb + l16];
                Lsc[qb + l16] = ls;         // total lsum for this z
                for (int dt = 0; dt < 4; ++dt)
                    for (int r = 0; r < 4; ++r) {
                        int idx = (qb + quad * 4 + r) * 65 + dt * 16 + l16;
                        Osc[idx] = o[g][dt][r] + Osc[idx];
                    }
            }
        }
        __syncthreads();
        // repack: contiguous bf16 partial rows [q][e] + fp32 lsum
        {
            const int q  = tid >> 2;
            const int e0 = (tid & 3) * 16;
            bf16x8 w0, w1;
            for (int i = 0; i < 8; ++i) {
                w0[i] = (bf16_t)Osc[q * 65 + e0 + i];
                w1[i] = (bf16_t)Osc[q * 65 + e0 + 8 + i];
            }
            size_t slot = ((size_t)(bh * 64 + qt)) * 4096 + q * 64 + e0;
            *(bf16x8*)&Op[slot]     = w0;
            *(bf16x8*)&Op[slot + 8] = w1;
            if (tid < 64) Lp[(bh * 64 + qt) * 64 + tid] = Lsc[tid];
        }
        // next leg's first __syncthreads() protects Osc/Lsc reuse
    }
}

// ---------------------------------------------------------------------------
extern "C" void kernel_launch(void* const* d_in, const int* in_sizes, int n_in,
                              void* d_out, int out_size, void* d_ws, size_t ws_size,
                              hipStream_t stream) {
    const float* q  = (const float*)d_in[0];
    const float* k  = (const float*)d_in[1];
    const float* v  = (const float*)d_in[2];
    const float* Wq = (const float*)d_in[3];
    const float* Wk = (const float*)d_in[4];
    const float* Wv = (const float*)d_in[5];
    const float* Wo = (const float*)d_in[6];
    float* out = (float*)d_out;

    bf16_t* ws = (bf16_t*)d_ws;
    const size_t R = (size_t)8192 * 512;   // 4.19M elems = 8.39 MB per region
    bf16_t* opart = ws + R;          // R1+R2: Opart z0/z1
    bf16_t* vh = ws + 3 * R;         // R3: V^T heads
    bf16_t* Wc = ws + 4 * R;         // +2 MB bf16 weights (Wq pre-scaled)
    float*  Lp = (float*)(ws + 4 * R + 1048576);  // +0.5 MB lsum partials
    bf16_t* qh = (bf16_t*)d_out;     // qh/kh in d_out, dead before final GEMM
    bf16_t* kh = (bf16_t*)d_out + R;

    cvt_W<<<dim3(512), dim3(256), 0, stream>>>(Wq, Wk, Wv, Wo, Wc);
    proj_fused<<<dim3(256, 1, 3), dim3(256), 0, stream>>>(q, k, v, Wc, qh, kh, vh);
    attn_kernel<<<dim3(1024), dim3(256), 0, stream>>>(qh, kh, vh, opart, Lp);
    gemm_final<<<dim3(1024), dim3(256), 0, stream>>>(opart, Lp, Wc + 3 * 262144, out);
}

// Round 14
// 230.103 us; speedup vs baseline: 1.4747x; 1.0020x over previous
//
#include <hip/hip_runtime.h>
#include <hip/hip_bf16.h>
#include <math.h>

typedef __bf16 bf16_t;
typedef __bf16 bf16x8 __attribute__((ext_vector_type(8)));
typedef __bf16 bf16x4 __attribute__((ext_vector_type(4)));
typedef short short4v __attribute__((ext_vector_type(4)));
typedef float f32x4 __attribute__((ext_vector_type(4)));

__device__ __forceinline__ f32x4 mfma_k32(bf16x8 a, bf16x8 b, f32x4 c) {
    return __builtin_amdgcn_mfma_f32_16x16x32_bf16(a, b, c, 0, 0, 0);
}

__device__ __forceinline__ f32x4 mfma_k16(bf16x4 a, bf16x4 b, f32x4 c) {
#if __has_builtin(__builtin_amdgcn_mfma_f32_16x16x16_bf16)
    return __builtin_amdgcn_mfma_f32_16x16x16_bf16(a, b, c, 0, 0, 0);
#elif __has_builtin(__builtin_amdgcn_mfma_f32_16x16x16bf16_1k)
    short4v as, bs;
    __builtin_memcpy(&as, &a, 8);
    __builtin_memcpy(&bs, &b, 8);
    return __builtin_amdgcn_mfma_f32_16x16x16bf16_1k(as, bs, c, 0, 0, 0);
#else
    f32x4 d = c;
    asm volatile("v_mfma_f32_16x16x16_bf16 %0, %1, %2, %0" : "+v"(d) : "v"(a), "v"(b));
    return d;
#endif
}

// raw v_exp_f32 (exp2): avoid OCML guard code around exp2f
__device__ __forceinline__ float fast_exp2(float x) {
#if __has_builtin(__builtin_amdgcn_exp2f)
    return __builtin_amdgcn_exp2f(x);
#else
    float r;
    asm("v_exp_f32 %0, %1" : "=v"(r) : "v"(x));
    return r;
#endif
}

// async global->LDS, 16B/lane; LDS dest = wave-uniform base + lane*16
__device__ __forceinline__ void async16(const bf16_t* g, __bf16* l) {
    __builtin_amdgcn_global_load_lds(
        (const __attribute__((address_space(1))) void*)g,
        (__attribute__((address_space(3))) void*)l, 16, 0, 0);
}

// XOR-swizzle: 16B chunks within each 64-col group, keyed by row&7 (global-side)
__device__ __forceinline__ int swz_col(int col, int row) {
    return (col & ~63) | ((((col >> 3) & 7) ^ (row & 7)) << 3) | (col & 7);
}

__device__ __forceinline__ bf16x8 cvt8(float4 a, float4 b) {
    bf16x8 w;
    w[0]=(__bf16)a.x; w[1]=(__bf16)a.y; w[2]=(__bf16)a.z; w[3]=(__bf16)a.w;
    w[4]=(__bf16)b.x; w[5]=(__bf16)b.y; w[6]=(__bf16)b.z; w[7]=(__bf16)b.w;
    return w;
}

// ---------------------------------------------------------------------------
// fp32 -> bf16 swizzled convert, W only (R7 lesson: keep this kernel).
// ---------------------------------------------------------------------------
__global__ __launch_bounds__(256) void cvt_W(const float* __restrict__ Wq,
                                             const float* __restrict__ Wk,
                                             const float* __restrict__ Wv,
                                             const float* __restrict__ Wo,
                                             bf16_t* __restrict__ Wc) {
    const int b2 = blockIdx.x;
    const int m = b2 >> 7;                   // which W
    const float* src = m == 0 ? Wq : m == 1 ? Wk : m == 2 ? Wv : Wo;
    const float sc = (m == 0) ? 0.125f * 1.44269504088896f : 1.0f;
    size_t i = ((size_t)(b2 & 127) * 256 + threadIdx.x) * 8;
    int row = (int)(i >> 9), col = (int)(i & 511);
    float4 a0 = *(const float4*)(src + i), a1 = *(const float4*)(src + i + 4);
    bf16x8 o;
    o[0]=(__bf16)(a0.x*sc); o[1]=(__bf16)(a0.y*sc); o[2]=(__bf16)(a0.z*sc); o[3]=(__bf16)(a0.w*sc);
    o[4]=(__bf16)(a1.x*sc); o[5]=(__bf16)(a1.y*sc); o[6]=(__bf16)(a1.z*sc); o[7]=(__bf16)(a1.w*sc);
    *(bf16x8*)(Wc + (size_t)m * 262144 + (size_t)row * 512 + swz_col(col, row)) = o;
}

// ---------------------------------------------------------------------------
// 128x128-tile NT GEMM, BK=128 two 64-wide sub-tiles (R13 winner) + T14
// async-STAGE split on the fp32 operand (R14): the fp32 reg-loads for step
// t+1 are issued AFTER the staged barrier, so their ~900cy HBM latency flies
// under step t's 32 MFMA instead of stalling the ds_write between barriers.
// Register audit (R9 lesson): +64 VGPR prefetch state; proj was 132 VGPR,
// LDS (64KB) already caps at 2 blocks/CU = 2 waves/SIMD = 256-VGPR budget,
// so 196 fits with zero occupancy loss. bf16 operand keeps global_load_lds
// (L2-resident W, cheap drain). Exactly one operand is fp32 per
// instantiation (AF32 xor BF32).
// ---------------------------------------------------------------------------
template<int MODE, int AF32, int BF32>
__device__ __forceinline__ void gemm128_body(__bf16* __restrict__ Asm0,
                                             __bf16* __restrict__ Asm1,
                                             __bf16* __restrict__ Bsm0,
                                             __bf16* __restrict__ Bsm1,
                                             const bf16_t* __restrict__ Ab,
                                             const float* __restrict__ Af,
                                             const bf16_t* __restrict__ Bb,
                                             const float* __restrict__ Bf,
                                             void* __restrict__ outp,
                                             int m0, int n0) {
    const int tid  = threadIdx.x;
    const int wave = tid >> 6;
    const int lane = tid & 63;
    const int quad = lane >> 4;
    const int l16  = lane & 15;
    const int swz  = l16 & 7;
    const int r8 = lane >> 3;
    const int c8 = (lane & 7) * 8;
    const int mrow0 = (wave & 1) * 64;
    const int ncol0 = (wave >> 1) * 64;
    const int wswz = ((lane & 7) ^ r8) << 3;

    // fp32-operand geometry (compile-time selected)
    const float* Gf = AF32 ? Af : Bf;
    const int    prow0 = AF32 ? m0 : n0;
    // bf16-operand geometry
    const bf16_t* Gb = AF32 ? Bb : Ab;
    const int     brow0 = AF32 ? n0 : m0;

    f32x4 acc[4][4];
    for (int i = 0; i < 4; ++i)
        for (int j = 0; j < 4; ++j) acc[i][j] = (f32x4){0.f, 0.f, 0.f, 0.f};

    float4 pre[8][2];                       // 64 VGPR: 2 sub-tiles x 4 row-grp
    // prologue: step-0 fp32 loads
#pragma unroll
    for (int sub = 0; sub < 2; ++sub)
#pragma unroll
        for (int j = 0; j < 4; ++j) {
            const int rl = wave * 32 + j * 8 + r8;
            const float* s = Gf + (size_t)(prow0 + rl) * 512 + sub * 64 + c8;
            pre[sub * 4 + j][0] = *(const float4*)s;
            pre[sub * 4 + j][1] = *(const float4*)(s + 4);
        }

    for (int kt = 0; kt < 512; kt += 128) {
        __syncthreads();
        // commit prefetched fp32 into its LDS sub-tiles (swizzled ds_write)
        {
            __bf16* F0 = AF32 ? Asm0 : Bsm0;
            __bf16* F1 = AF32 ? Asm1 : Bsm1;
#pragma unroll
            for (int sub = 0; sub < 2; ++sub) {
                __bf16* Fs = sub ? F1 : F0;
#pragma unroll
                for (int j = 0; j < 4; ++j) {
                    const int rl = wave * 32 + j * 8 + r8;
                    *(bf16x8*)&Fs[rl * 64 + wswz] = cvt8(pre[sub * 4 + j][0], pre[sub * 4 + j][1]);
                }
            }
        }
        // bf16 operand: global_load_lds direct
        {
            __bf16* B0 = AF32 ? Bsm0 : Asm0;
            __bf16* B1 = AF32 ? Bsm1 : Asm1;
#pragma unroll
            for (int sub = 0; sub < 2; ++sub) {
                __bf16* Bs2 = sub ? B1 : B0;
#pragma unroll
                for (int j = 0; j < 4; ++j) {
                    const int rl = wave * 32 + j * 8 + r8;
                    async16(Gb + (size_t)(brow0 + rl) * 512 + kt + sub * 64 + c8,
                            &Bs2[(wave * 32 + j * 8) * 64]);
                }
            }
        }
        __syncthreads();
        // T14: issue next step's fp32 loads — fly under this step's MFMA
        if (kt < 384) {
#pragma unroll
            for (int sub = 0; sub < 2; ++sub)
#pragma unroll
                for (int j = 0; j < 4; ++j) {
                    const int rl = wave * 32 + j * 8 + r8;
                    const float* s = Gf + (size_t)(prow0 + rl) * 512 + (kt + 128) + sub * 64 + c8;
                    pre[sub * 4 + j][0] = *(const float4*)s;
                    pre[sub * 4 + j][1] = *(const float4*)(s + 4);
                }
        }

#pragma unroll
        for (int half = 0; half < 2; ++half) {
            const __bf16* As = half ? Asm1 : Asm0;
            const __bf16* Bs = half ? Bsm1 : Bsm0;
            for (int ks = 0; ks < 2; ++ks) {
                bf16x8 af[4];
                for (int mt = 0; mt < 4; ++mt)
                    af[mt] = *(const bf16x8*)&As[(mrow0 + mt * 16 + l16) * 64 + ((ks * 4 + quad) ^ swz) * 8];
                for (int nt = 0; nt < 4; ++nt) {
                    bf16x8 bf = *(const bf16x8*)&Bs[(ncol0 + nt * 16 + l16) * 64 + ((ks * 4 + quad) ^ swz) * 8];
                    for (int mt = 0; mt < 4; ++mt)
                        acc[mt][nt] = mfma_k32(af[mt], bf, acc[mt][nt]);
                }
            }
        }
    }

    if (MODE == 0) {
        bf16_t* out = (bf16_t*)outp;
        for (int nt = 0; nt < 4; ++nt) {
            int e = n0 + ncol0 + nt * 16 + l16;
            int h = e >> 6, el = e & 63;
            for (int mt = 0; mt < 4; ++mt)
                for (int r = 0; r < 4; ++r) {
                    int row = m0 + mrow0 + mt * 16 + quad * 4 + r;   // b*4096+s
                    int b = row >> 12, s = row & 4095;
                    int elp = (((el >> 3) ^ (row & 7)) << 3) | (el & 7);
                    out[(((size_t)(b * 8 + h)) * 4096 + s) * 64 + elp] = (bf16_t)acc[mt][nt][r];
                }
        }
    } else {
        bf16_t* out = (bf16_t*)outp;
        for (int nt = 0; nt < 4; ++nt) {
            int s_g = n0 + ncol0 + nt * 16 + l16;
            int b = s_g >> 12;
            int sbase = (s_g & 4095) & ~63;
            int f = 16 * ((l16 >> 2) & 3) + 4 * nt + (l16 & 3);
            for (int mt = 0; mt < 4; ++mt)
                for (int r = 0; r < 4; ++r) {
                    int e_g = m0 + mrow0 + mt * 16 + quad * 4 + r;
                    int h = e_g >> 6, el = e_g & 63;
                    int col = sbase | ((((f >> 3) ^ (e_g & 7)) & 7) << 3) | (f & 7);
                    out[(((size_t)(b * 8 + h)) * 64 + el) * 4096 + col] = (bf16_t)acc[mt][nt][r];
                }
        }
    }
}

// grid (256,1,3); XCD-sibling swizzle; single kernel-scope 64KB LDS shared
// by all instantiations (2 blocks/CU — R11 proved sufficient for proj).
__global__ __launch_bounds__(256) void proj_fused(const float* __restrict__ q,
                                                  const float* __restrict__ k,
                                                  const float* __restrict__ v,
                                                  const bf16_t* __restrict__ Wc,
                                                  bf16_t* __restrict__ qh,
                                                  bf16_t* __restrict__ kh,
                                                  bf16_t* __restrict__ vh) {
    __shared__ __bf16 Asm[2][128 * 64];
    __shared__ __bf16 Bsm[2][128 * 64];
    const int f = blockIdx.x;
    const int y = (f >> 3) & 3;
    const int x = (f & 7) | ((f >> 5) << 3);
    const int z = blockIdx.z;
    const bf16_t* W = Wc + (size_t)z * 262144;
    if (z == 0)
        gemm128_body<0, 1, 0>(Asm[0], Asm[1], Bsm[0], Bsm[1], nullptr, q, W, nullptr, qh, x * 128, y * 128);
    else if (z == 1)
        gemm128_body<0, 1, 0>(Asm[0], Asm[1], Bsm[0], Bsm[1], nullptr, k, W, nullptr, kh, x * 128, y * 128);
    else
        gemm128_body<1, 0, 1>(Asm[0], Asm[1], Bsm[0], Bsm[1], W, nullptr, nullptr, v, vh, y * 128, x * 128);
}

// ---------------------------------------------------------------------------
// Final GEMM, 64x64 tiles (R12) + BK=128 two sub-tiles (R14, R13's proven
// barrier-halving applied here): drains 8 -> 4. LDS 32KB -> still 4
// blocks/CU at grid 1024. Per step, each half covers one head h.
// Fused z-combine + softmax normalization in A-staging; B = pre-converted
// bf16 Wo via async16; XCD swizzle.
// ---------------------------------------------------------------------------
__global__ __launch_bounds__(256) void gemm_final(const bf16_t* __restrict__ Op,
                                                  const float* __restrict__ Lp,
                                                  const bf16_t* __restrict__ B,
                                                  float* __restrict__ out) {
    __shared__ __bf16 Asm[2][64 * 64];
    __shared__ __bf16 Bsm[2][64 * 64];
    const int fb = blockIdx.x;
    const int yb = (fb >> 3) & 7;
    const int xb = (fb & 7) | ((fb >> 6) << 3);
    const int m0 = xb * 64;
    const int n0 = yb * 64;
    const int tid  = threadIdx.x;
    const int wave = tid >> 6;
    const int lane = tid & 63;
    const int quad = lane >> 4;
    const int l16  = lane & 15;
    const int swz  = l16 & 7;
    const int r8 = lane >> 3;
    const int c8 = (lane & 7) * 8;
    const int mrow0 = (wave & 1) * 32;
    const int ncol0 = (wave >> 1) * 32;
    const int wswz = ((lane & 7) ^ r8) << 3;

    f32x4 acc[2][2];
    for (int i = 0; i < 2; ++i)
        for (int j = 0; j < 2; ++j) acc[i][j] = (f32x4){0.f, 0.f, 0.f, 0.f};

    for (int kt = 0; kt < 512; kt += 128) {
        __syncthreads();
#pragma unroll
        for (int half = 0; half < 2; ++half) {
            const int h = (kt >> 6) + half;
            for (int j = 0; j < 2; ++j)
                async16(B + (size_t)(n0 + wave * 16 + j * 8 + r8) * 512 + kt + half * 64 + c8,
                        &Bsm[half][(wave * 16 + j * 8) * 64]);
            for (int j = 0; j < 2; ++j) {
                const int rl  = wave * 16 + j * 8 + r8;
                const int row = m0 + rl;                 // b*4096 + s
                const int b   = row >> 12, sp = row & 4095;
                const size_t lidx = (size_t)(b * 8 + h) * 4096 + sp;
                bf16x8 a0 = *(const bf16x8*)(Op + lidx * 64 + c8);
                bf16x8 a1 = *(const bf16x8*)(Op + 4194304 + lidx * 64 + c8);
                float inv = 1.0f / (Lp[lidx] + Lp[65536 + lidx]);
                bf16x8 w;
                for (int i = 0; i < 8; ++i)
                    w[i] = (bf16_t)(((float)a0[i] + (float)a1[i]) * inv);
                *(bf16x8*)&Asm[half][rl * 64 + wswz] = w;
            }
        }
        __syncthreads();

#pragma unroll
        for (int half = 0; half < 2; ++half) {
            for (int ks = 0; ks < 2; ++ks) {
                bf16x8 af[2];
                for (int mt = 0; mt < 2; ++mt)
                    af[mt] = *(const bf16x8*)&Asm[half][(mrow0 + mt * 16 + l16) * 64 + ((ks * 4 + quad) ^ swz) * 8];
                for (int nt = 0; nt < 2; ++nt) {
                    bf16x8 bf = *(const bf16x8*)&Bsm[half][(ncol0 + nt * 16 + l16) * 64 + ((ks * 4 + quad) ^ swz) * 8];
                    for (int mt = 0; mt < 2; ++mt)
                        acc[mt][nt] = mfma_k32(af[mt], bf, acc[mt][nt]);
                }
            }
        }
    }

    for (int nt = 0; nt < 2; ++nt) {
        int n = n0 + ncol0 + nt * 16 + l16;
        for (int mt = 0; mt < 2; ++mt)
            for (int r = 0; r < 4; ++r) {
                int row = m0 + mrow0 + mt * 16 + quad * 4 + r;
                out[(size_t)row * 512 + n] = acc[mt][nt][r];
            }
    }
}

// ---------------------------------------------------------------------------
// Causal flash attention v7 (verbatim R2/R5 winner, 62.2-62.6us): FROZEN.
// Four restructure attempts failed; root cause: 64 VGPR + 64 AGPR = the
// full 128-reg budget at (256,4) — any added live state spills.
// ---------------------------------------------------------------------------
__global__ __launch_bounds__(256, 4) void attn_kernel(const bf16_t* __restrict__ qh,
                                                      const bf16_t* __restrict__ kh,
                                                      const bf16_t* __restrict__ vh,
                                                      bf16_t* __restrict__ Opart,
                                                      float* __restrict__ Lpart) {
    __shared__ __bf16 SM[16384];            // 32 KB: K panels [2][64][64] + V panels
    __bf16* KSM = &SM[0];
    __bf16* VSM = &SM[8192];
    float* Osc = (float*)SM;                // 16.6 KB leg-end scratch [q][65]
    float* Lsc = (float*)&SM[8320];         // 256 B lsum scratch [q] (byte 16640)

    const int id   = blockIdx.x;
    const int bh   = ((id & 7) << 1) | ((id >> 3) & 1);   // XCD-grouped
    const int pair = (id >> 4) & 31;
    const int z    = (id >> 9) & 1;

    const int tid  = threadIdx.x;
    const int wave = tid >> 6;
    const int g2   = wave >> 1;             // K-panel parity within step
    const int wl   = wave & 1;              // query half
    const int lane = tid & 63;
    const int quad = lane >> 4;
    const int l16  = lane & 15;
    const int swz  = l16 & 7;
    const size_t base = (size_t)bh * 4096 * 64;
    const int r8 = lane >> 3;
    const int c8 = (lane & 7) * 8;

    bf16_t* Op = Opart + (size_t)z * 4194304;
    float*  Lp = Lpart + z * 65536;

    for (int leg = 0; leg < 2; ++leg) {
        const int qt = leg ? (63 - pair) : pair;
        const int q0 = qt * 64;

        bf16x8 qf[2][2];
        for (int g = 0; g < 2; ++g) {
            const bf16_t* qp = qh + base + (size_t)(q0 + wl * 32 + g * 16 + l16) * 64;
            qf[g][0] = *(const bf16x8*)(qp + ((quad ^ swz) * 8));
            qf[g][1] = *(const bf16x8*)(qp + (((4 + quad) ^ swz) * 8));
        }

        f32x4 o[2][4];
        for (int g = 0; g < 2; ++g)
            for (int i = 0; i < 4; ++i) o[g][i] = (f32x4){0.f, 0.f, 0.f, 0.f};
        float lsum[2] = {0.f, 0.f};

        const int S  = (qt + 2) >> 1;       // total 128-key steps of this leg
        const int Sh = (S + 1) >> 1;        // z=0 takes [0,Sh), z=1 takes [Sh,S)
        const int it0 = z ? Sh : 0;
        const int it1 = z ? S : Sh;

        for (int it = it0; it < it1; ++it) {
            const int j0 = it * 128;
            __syncthreads();
            for (int p = 0; p < 2; ++p)
                for (int j = 0; j < 2; ++j) {
                    int row = wave * 16 + j * 8 + r8;
                    async16(kh + base + (size_t)(j0 + p * 64 + row) * 64 + c8,
                            KSM + (p * 64 + wave * 16 + j * 8) * 64);
                    async16(vh + (size_t)(bh * 64 + row) * 4096 + j0 + p * 64 + c8,
                            VSM + (p * 64 + wave * 16 + j * 8) * 64);
                }
            __syncthreads();

            const int pp = g2;
            const int koff = j0 + pp * 64 - q0;
            if (koff > wl * 32 + 31) continue;     // fully masked for this wave

            // S^T = K·Q^T (C: col=query=l16, row=key=nt*16+quad*4+r)
            f32x4 st[2][4];
            for (int nt = 0; nt < 4; ++nt) {
                const __bf16* kr = KSM + (pp * 64 + nt * 16 + l16) * 64;
                bf16x8 kf0 = *(const bf16x8*)(kr + ((quad ^ swz) * 8));
                bf16x8 kf1 = *(const bf16x8*)(kr + (((4 + quad) ^ swz) * 8));
                for (int g = 0; g < 2; ++g) {
                    f32x4 zz = (f32x4){0.f, 0.f, 0.f, 0.f};
                    zz = mfma_k32(kf0, qf[g][0], zz);
                    zz = mfma_k32(kf1, qf[g][1], zz);
                    st[g][nt] = zz;
                }
            }

            // fixed-base softmax: p = exp2(st)
            bf16x4 pf[2][4];
            for (int g = 0; g < 2; ++g) {
                const int qb = wl * 32 + g * 16;
                if (koff + 63 <= qb) {
                    for (int nt = 0; nt < 4; ++nt)
                        for (int r = 0; r < 4; ++r) {
                            float p = fast_exp2(st[g][nt][r]);
                            lsum[g] += p;
                            pf[g][nt][r] = (bf16_t)p;
                        }
                } else {
                    const int qrow = qb + l16;
                    for (int nt = 0; nt < 4; ++nt)
                        for (int r = 0; r < 4; ++r) {
                            int key = nt * 16 + quad * 4 + r;
                            float p = (key + koff <= qrow) ? fast_exp2(st[g][nt][r]) : 0.f;
                            lsum[g] += p;
                            pf[g][nt][r] = (bf16_t)p;
                        }
                }
            }

            // O += P·V (P register-resident)
            for (int dt = 0; dt < 4; ++dt)
                for (int kt2 = 0; kt2 < 2; ++kt2) {
                    bf16x8 vf = *(const bf16x8*)&VSM[(pp * 64 + dt * 16 + l16) * 64 + (((2 * quad + kt2) ^ swz) * 8)];
                    bf16x4 vlo = {vf[0], vf[1], vf[2], vf[3]};
                    bf16x4 vhi = {vf[4], vf[5], vf[6], vf[7]};
                    for (int g = 0; g < 2; ++g) {
                        o[g][dt] = mfma_k16(pf[g][2 * kt2], vlo, o[g][dt]);
                        o[g][dt] = mfma_k16(pf[g][2 * kt2 + 1], vhi, o[g][dt]);
                    }
                }
        }

        // ---- combine K-parity partials within block, write leg partials ----
        __syncthreads();                    // all K/V LDS reads done
        if (g2 == 1) {
            for (int g = 0; g < 2; ++g) {
                float ls = lsum[g];
                ls += __shfl_xor(ls, 16);
                ls += __shfl_xor(ls, 32);
                const int qb = wl * 32 + g * 16;
                Lsc[qb + l16] = ls;
                for (int dt = 0; dt < 4; ++dt)
                    for (int r = 0; r < 4; ++r)
                        Osc[(qb + quad * 4 + r) * 65 + dt * 16 + l16] = o[g][dt][r];
            }
        }
        __syncthreads();
        if (g2 == 0) {
            for (int g = 0; g < 2; ++g) {
                float ls = lsum[g];
                ls += __shfl_xor(ls, 16);
                ls += __shfl_xor(ls, 32);
                const int qb = wl * 32 + g * 16;
                ls += Lsc[qb + l16];
                Lsc[qb + l16] = ls;         // total lsum for this z
                for (int dt = 0; dt < 4; ++dt)
                    for (int r = 0; r < 4; ++r) {
                        int idx = (qb + quad * 4 + r) * 65 + dt * 16 + l16;
                        Osc[idx] = o[g][dt][r] + Osc[idx];
                    }
            }
        }
        __syncthreads();
        // repack: contiguous bf16 partial rows [q][e] + fp32 lsum
        {
            const int q  = tid >> 2;
            const int e0 = (tid & 3) * 16;
            bf16x8 w0, w1;
            for (int i = 0; i < 8; ++i) {
                w0[i] = (bf16_t)Osc[q * 65 + e0 + i];
                w1[i] = (bf16_t)Osc[q * 65 + e0 + 8 + i];
            }
            size_t slot = ((size_t)(bh * 64 + qt)) * 4096 + q * 64 + e0;
            *(bf16x8*)&Op[slot]     = w0;
            *(bf16x8*)&Op[slot + 8] = w1;
            if (tid < 64) Lp[(bh * 64 + qt) * 64 + tid] = Lsc[tid];
        }
        // next leg's first __syncthreads() protects Osc/Lsc reuse
    }
}

// ---------------------------------------------------------------------------
extern "C" void kernel_launch(void* const* d_in, const int* in_sizes, int n_in,
                              void* d_out, int out_size, void* d_ws, size_t ws_size,
                              hipStream_t stream) {
    const float* q  = (const float*)d_in[0];
    const float* k  = (const float*)d_in[1];
    const float* v  = (const float*)d_in[2];
    const float* Wq = (const float*)d_in[3];
    const float* Wk = (const float*)d_in[4];
    const float* Wv = (const float*)d_in[5];
    const float* Wo = (const float*)d_in[6];
    float* out = (float*)d_out;

    bf16_t* ws = (bf16_t*)d_ws;
    const size_t R = (size_t)8192 * 512;   // 4.19M elems = 8.39 MB per region
    bf16_t* opart = ws + R;          // R1+R2: Opart z0/z1
    bf16_t* vh = ws + 3 * R;         // R3: V^T heads
    bf16_t* Wc = ws + 4 * R;         // +2 MB bf16 weights (Wq pre-scaled)
    float*  Lp = (float*)(ws + 4 * R + 1048576);  // +0.5 MB lsum partials
    bf16_t* qh = (bf16_t*)d_out;     // qh/kh in d_out, dead before final GEMM
    bf16_t* kh = (bf16_t*)d_out + R;

    cvt_W<<<dim3(512), dim3(256), 0, stream>>>(Wq, Wk, Wv, Wo, Wc);
    proj_fused<<<dim3(256, 1, 3), dim3(256), 0, stream>>>(q, k, v, Wc, qh, kh, vh);
    attn_kernel<<<dim3(1024), dim3(256), 0, stream>>>(qh, kh, vh, opart, Lp);
    gemm_final<<<dim3(1024), dim3(256), 0, stream>>>(opart, Lp, Wc + 3 * 262144, out);
}